// Round 2
// baseline (3456.739 us; speedup 1.0000x reference)
//
#include <hip/hip_runtime.h>
#include <math.h>

// Problem constants
// B=4 S=4096 D=768 H=8 BS=64 NB=64 NKB=5 HD=96 DFF=3072
static constexpr int Bb   = 4;
static constexpr int Ss   = 4096;
static constexpr int Dd   = 768;
static constexpr int Hh   = 8;
static constexpr int NBK  = 64;   // number of 64-row blocks along S
static constexpr int HDm  = 96;
static constexpr int DFFc = 3072;
static constexpr int MROWS = Bb * Ss;  // 16384

// ---------------------------------------------------------------------------
// LayerNorm: one block (192 threads = 3 waves) per row of 768 floats.
// ---------------------------------------------------------------------------
__global__ __launch_bounds__(192)
void ln_kernel(const float* __restrict__ x, const float* __restrict__ g,
               const float* __restrict__ beta, float* __restrict__ out) {
  const int row = blockIdx.x;
  const int t = threadIdx.x;
  const float* xr = x + (size_t)row * Dd;
  float4 v = *(const float4*)(xr + t * 4);
  float s  = v.x + v.y + v.z + v.w;
  float sq = v.x * v.x + v.y * v.y + v.z * v.z + v.w * v.w;
#pragma unroll
  for (int o = 32; o; o >>= 1) {
    s  += __shfl_xor(s, o);
    sq += __shfl_xor(sq, o);
  }
  __shared__ float rs[4], rq[4];
  const int w = t >> 6;
  if ((t & 63) == 0) { rs[w] = s; rq[w] = sq; }
  __syncthreads();
  s  = rs[0] + rs[1] + rs[2];
  sq = rq[0] + rq[1] + rq[2];
  const float mean = s * (1.0f / Dd);
  const float var  = sq * (1.0f / Dd) - mean * mean;
  const float rstd = rsqrtf(var + 1e-5f);
  float4 gv = *(const float4*)(g + t * 4);
  float4 bv = *(const float4*)(beta + t * 4);
  float4 o;
  o.x = (v.x - mean) * rstd * gv.x + bv.x;
  o.y = (v.y - mean) * rstd * gv.y + bv.y;
  o.z = (v.z - mean) * rstd * gv.z + bv.z;
  o.w = (v.w - mean) * rstd * gv.w + bv.w;
  *(float4*)(out + (size_t)row * Dd + t * 4) = o;
}

// ---------------------------------------------------------------------------
// FP32 SGEMM: C[M,N] = act(A[M,K] @ W[K,N] + bias (+ resid))
// 128x128 tile, BK=16, 256 threads, 8x8 per-thread microtile.
// resid may alias C (each element read-then-written by its owning thread).
// ---------------------------------------------------------------------------
template <int RELU>
__global__ __launch_bounds__(256)
void gemm_kernel(const float* __restrict__ A, const float* __restrict__ W,
                 const float* __restrict__ bias, const float* __restrict__ resid,
                 float* __restrict__ C, int M, int N, int K) {
  __shared__ float As[16][128];   // A transposed: As[k][m]
  __shared__ float Bs[16][128];   // Bs[k][n]
  const int tid = threadIdx.x;
  const int n0 = blockIdx.x * 128;
  const int m0 = blockIdx.y * 128;
  const int tx = tid & 15;        // n-dir
  const int ty = tid >> 4;        // m-dir
  const int arow = tid & 127;
  const int akk  = (tid >> 7) * 8;
  const int brow = tid >> 4;      // k row for B load
  const int bnn  = (tid & 15) * 8;
  const float* Ap = A + (size_t)(m0 + arow) * K + akk;
  const float* Wp = W + (size_t)brow * N + n0 + bnn;

  float acc[8][8];
#pragma unroll
  for (int i = 0; i < 8; i++)
#pragma unroll
    for (int j = 0; j < 8; j++) acc[i][j] = 0.0f;

  for (int k0 = 0; k0 < K; k0 += 16) {
    float4 a0 = *(const float4*)(Ap + k0);
    float4 a1 = *(const float4*)(Ap + k0 + 4);
    float4 b0 = *(const float4*)(Wp + (size_t)k0 * N);
    float4 b1 = *(const float4*)(Wp + (size_t)k0 * N + 4);
    __syncthreads();
    As[akk + 0][arow] = a0.x; As[akk + 1][arow] = a0.y;
    As[akk + 2][arow] = a0.z; As[akk + 3][arow] = a0.w;
    As[akk + 4][arow] = a1.x; As[akk + 5][arow] = a1.y;
    As[akk + 6][arow] = a1.z; As[akk + 7][arow] = a1.w;
    *(float4*)&Bs[brow][bnn]     = b0;
    *(float4*)&Bs[brow][bnn + 4] = b1;
    __syncthreads();
#pragma unroll
    for (int kk = 0; kk < 16; kk++) {
      float a[8], b[8];
      *(float4*)(a)     = *(const float4*)&As[kk][ty * 8];
      *(float4*)(a + 4) = *(const float4*)&As[kk][ty * 8 + 4];
      *(float4*)(b)     = *(const float4*)&Bs[kk][tx * 8];
      *(float4*)(b + 4) = *(const float4*)&Bs[kk][tx * 8 + 4];
#pragma unroll
      for (int i = 0; i < 8; i++)
#pragma unroll
        for (int j = 0; j < 8; j++)
          acc[i][j] = fmaf(a[i], b[j], acc[i][j]);
    }
  }

  float bb[8];
  {
    float4 bi0 = *(const float4*)(bias + n0 + tx * 8);
    float4 bi1 = *(const float4*)(bias + n0 + tx * 8 + 4);
    bb[0] = bi0.x; bb[1] = bi0.y; bb[2] = bi0.z; bb[3] = bi0.w;
    bb[4] = bi1.x; bb[5] = bi1.y; bb[6] = bi1.z; bb[7] = bi1.w;
  }
#pragma unroll
  for (int i = 0; i < 8; i++) {
    const size_t off = (size_t)(m0 + ty * 8 + i) * N + n0 + tx * 8;
    float o[8];
#pragma unroll
    for (int j = 0; j < 8; j++) o[j] = acc[i][j] + bb[j];
    if (resid) {
      float4 r0 = *(const float4*)(resid + off);
      float4 r1 = *(const float4*)(resid + off + 4);
      o[0] += r0.x; o[1] += r0.y; o[2] += r0.z; o[3] += r0.w;
      o[4] += r1.x; o[5] += r1.y; o[6] += r1.z; o[7] += r1.w;
    }
    if (RELU) {
#pragma unroll
      for (int j = 0; j < 8; j++) o[j] = fmaxf(o[j], 0.0f);
    }
    float4 s0, s1;
    s0.x = o[0]; s0.y = o[1]; s0.z = o[2]; s0.w = o[3];
    s1.x = o[4]; s1.y = o[5]; s1.z = o[6]; s1.w = o[7];
    *(float4*)(C + off)     = s0;
    *(float4*)(C + off + 4) = s1;
  }
}

// ---------------------------------------------------------------------------
// BigBird block-sparse attention. Grid: (B*H*NB, 2). Block: 256 threads.
// Each block: 32 query rows of one (b,h,n) block; loops over 5 key-block
// slots with online softmax (flash-style). Mask computed analytically:
//   slot valid  <=>  s==0 || kb!=0
//   diag (kb==n) => within-block causal p <= q
// ctx may alias qh: each block reads only its own 32 q-rows (at start) and
// writes exactly those rows (at end); blocks cover disjoint row sets.
// ---------------------------------------------------------------------------
__global__ __launch_bounds__(256)
void attn_kernel(const float* __restrict__ qh, const float* __restrict__ kh,
                 const float* __restrict__ vh, const int* __restrict__ kbidx,
                 float* __restrict__ ctx) {
  const int bid = blockIdx.x;
  const int n = bid & 63;
  const int h = (bid >> 6) & 7;
  const int b = bid >> 9;
  const int qr0 = blockIdx.y * 32;
  const int tid = threadIdx.x;

  __shared__ float qs[32][100];     // padded (stride 100) for alignment
  __shared__ float kv[64][100];     // K or V slot tile
  __shared__ float ss[32][68];      // scores/probs for current slot
  __shared__ float mrow[32], lrow[32], frow[32];

  // Load Q block (32 rows x 96)
  {
    const int r = tid >> 3;
    const int cc = (tid & 7) * 12;
    const float* src =
        qh + ((size_t)(b * Ss) + n * 64 + qr0 + r) * Dd + h * HDm + cc;
    float4 v0 = *(const float4*)(src);
    float4 v1 = *(const float4*)(src + 4);
    float4 v2 = *(const float4*)(src + 8);
    *(float4*)&qs[r][cc]     = v0;
    *(float4*)&qs[r][cc + 4] = v1;
    *(float4*)&qs[r][cc + 8] = v2;
  }
  if (tid < 32) { mrow[tid] = -INFINITY; lrow[tid] = 0.0f; }
  float acc[12];
#pragma unroll
  for (int i = 0; i < 12; i++) acc[i] = 0.0f;
  const float scale = 0.1020620726f;  // 1/sqrt(96)
  __syncthreads();

  for (int s = 0; s < 5; s++) {
    const int kb = kbidx[n * 5 + s];
    if (!(s == 0 || kb != 0)) continue;  // invalid slot (uniform branch)
    const bool diag = (kb == n);

    // Load K slot tile (64 x 96)
    {
      const int r = tid >> 2;
      const int cc = (tid & 3) * 24;
      const float* src =
          kh + ((size_t)(b * Ss) + kb * 64 + r) * Dd + h * HDm + cc;
#pragma unroll
      for (int u = 0; u < 6; u++)
        *(float4*)&kv[r][cc + u * 4] = *(const float4*)(src + u * 4);
    }
    __syncthreads();

    // Scores: each thread computes 2 rows x 4 key-cols
    {
      const int r0 = (tid & 15) * 2;
      const int pb = (tid >> 4) * 4;
      float sc[2][4];
#pragma unroll
      for (int i = 0; i < 2; i++)
#pragma unroll
        for (int j = 0; j < 4; j++) sc[i][j] = 0.0f;
      for (int kk = 0; kk < 96; kk += 4) {
        float4 q0 = *(const float4*)&qs[r0][kk];
        float4 q1 = *(const float4*)&qs[r0 + 1][kk];
#pragma unroll
        for (int j = 0; j < 4; j++) {
          float4 kr = *(const float4*)&kv[pb + j][kk];
          sc[0][j] += q0.x * kr.x + q0.y * kr.y + q0.z * kr.z + q0.w * kr.w;
          sc[1][j] += q1.x * kr.x + q1.y * kr.y + q1.z * kr.z + q1.w * kr.w;
        }
      }
#pragma unroll
      for (int i = 0; i < 2; i++)
#pragma unroll
        for (int j = 0; j < 4; j++) {
          float v = sc[i][j] * scale;
          if (diag && (pb + j) > (qr0 + r0 + i)) v = -1e9f;
          ss[r0 + i][pb + j] = v;
        }
    }
    __syncthreads();

    // Online-softmax update: 8 threads per row, 8 entries each
    {
      const int r = tid >> 3;
      const int sub = tid & 7;
      float vals[8];
      float mt = -INFINITY;
#pragma unroll
      for (int j = 0; j < 8; j++) {
        vals[j] = ss[r][sub + 8 * j];
        mt = fmaxf(mt, vals[j]);
      }
#pragma unroll
      for (int o = 1; o < 8; o <<= 1) mt = fmaxf(mt, __shfl_xor(mt, o));
      const float mold = mrow[r];
      const float mnew = fmaxf(mold, mt);
      float psum = 0.0f;
#pragma unroll
      for (int j = 0; j < 8; j++) {
        float e = expf(vals[j] - mnew);
        ss[r][sub + 8 * j] = e;
        psum += e;
      }
#pragma unroll
      for (int o = 1; o < 8; o <<= 1) psum += __shfl_xor(psum, o);
      if (sub == 0) {
        const float f = expf(mold - mnew);  // mold=-inf on first slot -> 0
        lrow[r] = lrow[r] * f + psum;
        mrow[r] = mnew;
        frow[r] = f;
      }
    }
    __syncthreads();

    // Load V slot tile (overwrite kv)
    {
      const int r = tid >> 2;
      const int cc = (tid & 3) * 24;
      const float* src =
          vh + ((size_t)(b * Ss) + kb * 64 + r) * Dd + h * HDm + cc;
#pragma unroll
      for (int u = 0; u < 6; u++)
        *(float4*)&kv[r][cc + u * 4] = *(const float4*)(src + u * 4);
    }
    __syncthreads();

    // PV accumulate: each thread 1 row x 12 dims
    {
      const int r = tid & 31;
      const int d0 = (tid >> 5) * 12;
      const float f = frow[r];
#pragma unroll
      for (int i = 0; i < 12; i++) acc[i] *= f;
      for (int p = 0; p < 64; p++) {
        const float pr = ss[r][p];
        float4 v0 = *(const float4*)&kv[p][d0];
        float4 v1 = *(const float4*)&kv[p][d0 + 4];
        float4 v2 = *(const float4*)&kv[p][d0 + 8];
        acc[0] = fmaf(pr, v0.x, acc[0]);  acc[1] = fmaf(pr, v0.y, acc[1]);
        acc[2] = fmaf(pr, v0.z, acc[2]);  acc[3] = fmaf(pr, v0.w, acc[3]);
        acc[4] = fmaf(pr, v1.x, acc[4]);  acc[5] = fmaf(pr, v1.y, acc[5]);
        acc[6] = fmaf(pr, v1.z, acc[6]);  acc[7] = fmaf(pr, v1.w, acc[7]);
        acc[8] = fmaf(pr, v2.x, acc[8]);  acc[9] = fmaf(pr, v2.y, acc[9]);
        acc[10] = fmaf(pr, v2.z, acc[10]); acc[11] = fmaf(pr, v2.w, acc[11]);
      }
    }
    __syncthreads();
  }

  // Write ctx = acc / l
  {
    const int r = tid & 31;
    const int d0 = (tid >> 5) * 12;
    const float inv = 1.0f / lrow[r];
    float* dst = ctx + ((size_t)(b * Ss) + n * 64 + qr0 + r) * Dd + h * HDm + d0;
    float4 s0, s1, s2;
    s0.x = acc[0] * inv;  s0.y = acc[1] * inv;
    s0.z = acc[2] * inv;  s0.w = acc[3] * inv;
    s1.x = acc[4] * inv;  s1.y = acc[5] * inv;
    s1.z = acc[6] * inv;  s1.w = acc[7] * inv;
    s2.x = acc[8] * inv;  s2.y = acc[9] * inv;
    s2.z = acc[10] * inv; s2.w = acc[11] * inv;
    *(float4*)(dst)     = s0;
    *(float4*)(dst + 4) = s1;
    *(float4*)(dst + 8) = s2;
  }
}

// ---------------------------------------------------------------------------
// Host launcher.
// Workspace budget: 4 slabs x 48 MiB = 192 MiB total.
//   h   [0, SZ)      : LN output (reused for h2)
//   qh  [SZ, 2SZ)    : Q heads, then overwritten in-place by ctx
//   kh  [2SZ, 3SZ)   : K heads; after attention reused as FFN-chunk buffer
//   vh  [3SZ, 4SZ)   : V heads; after attention reused as FFN-chunk buffer
// x1 lives in d_out (written step 6, LN'd step 7, read+overwritten step 9).
// FFN runs in 2 chunks of 8192 rows; intermediate (8192x3072 = 96 MiB)
// occupies kh..vh.
// ---------------------------------------------------------------------------
extern "C" void kernel_launch(void* const* d_in, const int* in_sizes, int n_in,
                              void* d_out, int out_size, void* d_ws, size_t ws_size,
                              hipStream_t stream) {
  const float* x    = (const float*)d_in[0];
  const float* Wq   = (const float*)d_in[1];
  const float* bq   = (const float*)d_in[2];
  const float* Wk   = (const float*)d_in[3];
  const float* bk   = (const float*)d_in[4];
  const float* Wv   = (const float*)d_in[5];
  const float* bv   = (const float*)d_in[6];
  const float* Wo   = (const float*)d_in[7];
  const float* bo   = (const float*)d_in[8];
  const float* ln_g = (const float*)d_in[9];
  const float* ln_b = (const float*)d_in[10];
  const float* W1   = (const float*)d_in[11];
  const float* b1   = (const float*)d_in[12];
  const float* W2   = (const float*)d_in[13];
  const float* b2   = (const float*)d_in[14];
  const int*   kb   = (const int*)d_in[15];
  // d_in[16] = attn_mask (bool) — unused; mask derived analytically from kb_idx.

  float* out = (float*)d_out;
  float* ws  = (float*)d_ws;

  constexpr size_t SZ = (size_t)MROWS * Dd;  // 12,582,912 floats (48 MiB)
  float* h    = ws;
  float* qh   = h + SZ;
  float* kh   = qh + SZ;
  float* vh   = kh + SZ;
  float* ctxb = qh;          // in-place: ctx overwrites qh (disjoint per block)
  float* fbuf = kh;          // FFN chunk buffer (96 MiB = kh+vh)

  // 1. h = LN(x)
  ln_kernel<<<MROWS, 192, 0, stream>>>(x, ln_g, ln_b, h);

  // 2-4. QKV projections
  gemm_kernel<0><<<dim3(Dd / 128, MROWS / 128), 256, 0, stream>>>(
      h, Wq, bq, nullptr, qh, MROWS, Dd, Dd);
  gemm_kernel<0><<<dim3(Dd / 128, MROWS / 128), 256, 0, stream>>>(
      h, Wk, bk, nullptr, kh, MROWS, Dd, Dd);
  gemm_kernel<0><<<dim3(Dd / 128, MROWS / 128), 256, 0, stream>>>(
      h, Wv, bv, nullptr, vh, MROWS, Dd, Dd);

  // 5. BigBird attention (ctx -> qh in place)
  attn_kernel<<<dim3(Bb * Hh * NBK, 2), 256, 0, stream>>>(qh, kh, vh, kb, ctxb);

  // 6. out = x1 = x + ctx @ Wo + bo
  gemm_kernel<0><<<dim3(Dd / 128, MROWS / 128), 256, 0, stream>>>(
      ctxb, Wo, bo, x, out, MROWS, Dd, Dd);

  // 7. h = LN(x1)
  ln_kernel<<<MROWS, 192, 0, stream>>>(out, ln_g, ln_b, h);

  // 8-9. FFN in 2 chunks of 8192 rows (intermediate reuses kh+vh = 96 MiB)
  constexpr int CH = MROWS / 2;  // 8192
  for (int c = 0; c < 2; c++) {
    const float* hc  = h + (size_t)c * CH * Dd;
    float*       oc  = out + (size_t)c * CH * Dd;
    gemm_kernel<1><<<dim3(DFFc / 128, CH / 128), 256, 0, stream>>>(
        hc, W1, b1, nullptr, fbuf, CH, DFFc, Dd);
    gemm_kernel<0><<<dim3(Dd / 128, CH / 128), 256, 0, stream>>>(
        fbuf, W2, b2, oc, oc, CH, Dd, DFFc);
  }
}

// Round 5
// 1876.047 us; speedup vs baseline: 1.8426x; 1.8426x over previous
//
#include <hip/hip_runtime.h>
#include <math.h>

// B=4 S=4096 D=768 H=8 BS=64 NB=64 NKB=5 HD=96 DFF=3072
static constexpr int Bb   = 4;
static constexpr int Ss   = 4096;
static constexpr int Dd   = 768;
static constexpr int HDm  = 96;
static constexpr int DFFc = 3072;
static constexpr int MROWS = Bb * Ss;  // 16384
static constexpr int NBK  = 64;
static constexpr int Hh   = 8;

typedef float f32x4_t __attribute__((ext_vector_type(4)));
typedef short s16x8_t __attribute__((ext_vector_type(8)));

__device__ __forceinline__ unsigned short f2bf(float f) {
  union { float f; unsigned int u; } c; c.f = f;
  unsigned int u = c.u;
  unsigned int r = (u + 0x7FFFu + ((u >> 16) & 1u)) >> 16;
  return (unsigned short)r;
}
__device__ __forceinline__ float bf2f(unsigned short u) {
  union { unsigned int u; float f; } c; c.u = ((unsigned int)u) << 16;
  return c.f;
}

// ---------------------------------------------------------------------------
// Weight transpose+cast: src fp32 [K][N] -> dst bf16 [N][K]. 64x64 tiles.
// ---------------------------------------------------------------------------
__global__ __launch_bounds__(256)
void transpose_cast(const float* __restrict__ src, unsigned short* __restrict__ dst,
                    int K, int N) {
  __shared__ float t[64][65];
  const int n0 = blockIdx.x * 64, k0 = blockIdx.y * 64;
  const int tid = threadIdx.x;
  {
    const int r = tid >> 2, cs = (tid & 3) * 16;
    const float* sp = src + (size_t)(k0 + r) * N + n0 + cs;
#pragma unroll
    for (int u = 0; u < 4; u++) {
      float4 v = *(const float4*)(sp + u * 4);
      t[r][cs + u * 4 + 0] = v.x; t[r][cs + u * 4 + 1] = v.y;
      t[r][cs + u * 4 + 2] = v.z; t[r][cs + u * 4 + 3] = v.w;
    }
  }
  __syncthreads();
  {
    const int n = tid >> 2, ks = (tid & 3) * 16;
    unsigned short o[16];
#pragma unroll
    for (int j = 0; j < 16; j++) o[j] = f2bf(t[ks + j][n]);
    unsigned short* dp = dst + (size_t)(n0 + n) * K + k0 + ks;
    *(uint4*)(dp)     = *(uint4*)(o);
    *(uint4*)(dp + 8) = *(uint4*)(o + 8);
  }
}

// ---------------------------------------------------------------------------
// LayerNorm: fp32 in, bf16 out. 192 threads/row.
// ---------------------------------------------------------------------------
__global__ __launch_bounds__(192)
void ln_kernel(const float* __restrict__ x, const float* __restrict__ g,
               const float* __restrict__ beta, unsigned short* __restrict__ out) {
  const int row = blockIdx.x;
  const int t = threadIdx.x;
  const float* xr = x + (size_t)row * Dd;
  float4 v = *(const float4*)(xr + t * 4);
  float s  = v.x + v.y + v.z + v.w;
  float sq = v.x * v.x + v.y * v.y + v.z * v.z + v.w * v.w;
#pragma unroll
  for (int o = 32; o; o >>= 1) {
    s  += __shfl_xor(s, o);
    sq += __shfl_xor(sq, o);
  }
  __shared__ float rs[4], rq[4];
  const int w = t >> 6;
  if ((t & 63) == 0) { rs[w] = s; rq[w] = sq; }
  __syncthreads();
  s  = rs[0] + rs[1] + rs[2];
  sq = rq[0] + rq[1] + rq[2];
  const float mean = s * (1.0f / Dd);
  const float var  = sq * (1.0f / Dd) - mean * mean;
  const float rstd = rsqrtf(var + 1e-5f);
  float4 gv = *(const float4*)(g + t * 4);
  float4 bv = *(const float4*)(beta + t * 4);
  ushort4 o;
  o.x = f2bf((v.x - mean) * rstd * gv.x + bv.x);
  o.y = f2bf((v.y - mean) * rstd * gv.y + bv.y);
  o.z = f2bf((v.z - mean) * rstd * gv.z + bv.z);
  o.w = f2bf((v.w - mean) * rstd * gv.w + bv.w);
  *(ushort4*)(out + (size_t)row * Dd + t * 4) = o;
}

// ---------------------------------------------------------------------------
// BF16 MFMA GEMM: C[M,N] = act(A[M,K] @ Bt[N,K]^T + bias (+ fp32 resid))
// A, Bt bf16. Tile 128x128, BK=64, 256 threads (4 waves, 2x2), 64x64/wave.
// LDS rows padded to 72 ushorts (144B: 16B-aligned, 2-way max conflicts).
// Output: fp32 (Cf) or bf16 (Cb).
// ---------------------------------------------------------------------------
template <int RELU, int OUTBF16, int RESID>
__global__ __launch_bounds__(256)
void bgemm(const unsigned short* __restrict__ A, const unsigned short* __restrict__ Bt,
           const float* __restrict__ bias, const float* __restrict__ resid,
           float* __restrict__ Cf, unsigned short* __restrict__ Cb,
           int M, int N, int K) {
  constexpr int LDT = 72;
  __shared__ __align__(16) unsigned short As[128 * LDT];
  __shared__ __align__(16) unsigned short Bs[128 * LDT];
  const int tid = threadIdx.x;
  const int n0 = blockIdx.x * 128, m0 = blockIdx.y * 128;

  // staging: row = tid>>1 (0..127), half = (tid&1)*32 ushorts of the 64-k row
  const int srow = tid >> 1;
  const int shalf = (tid & 1) * 32;
  const unsigned short* Ap = A + (size_t)(m0 + srow) * K + shalf;
  const unsigned short* Bp = Bt + (size_t)(n0 + srow) * K + shalf;

  const int lane = tid & 63, w = tid >> 6;
  const int wr = (w >> 1) * 64, wc = (w & 1) * 64;
  const int fr = lane & 15, fq = lane >> 4;  // frag row/col, k-quarter

  f32x4_t acc[4][4];
#pragma unroll
  for (int i = 0; i < 4; i++)
#pragma unroll
    for (int j = 0; j < 4; j++) acc[i][j] = (f32x4_t)0.0f;

  uint4 ra[4], rb[4];
#pragma unroll
  for (int u = 0; u < 4; u++) {
    ra[u] = *(const uint4*)(Ap + u * 8);
    rb[u] = *(const uint4*)(Bp + u * 8);
  }

  for (int kt = 0; kt < K; kt += 64) {
    __syncthreads();  // protect LDS from previous compute
#pragma unroll
    for (int u = 0; u < 4; u++) {
      *(uint4*)&As[srow * LDT + shalf + u * 8] = ra[u];
      *(uint4*)&Bs[srow * LDT + shalf + u * 8] = rb[u];
    }
    __syncthreads();
    if (kt + 64 < K) {
#pragma unroll
      for (int u = 0; u < 4; u++) {
        ra[u] = *(const uint4*)(Ap + kt + 64 + u * 8);
        rb[u] = *(const uint4*)(Bp + kt + 64 + u * 8);
      }
    }
#pragma unroll
    for (int ks = 0; ks < 2; ks++) {
      s16x8_t af[4], bfr[4];
#pragma unroll
      for (int i = 0; i < 4; i++)
        af[i] = *(const s16x8_t*)&As[(wr + i * 16 + fr) * LDT + ks * 32 + fq * 8];
#pragma unroll
      for (int j = 0; j < 4; j++)
        bfr[j] = *(const s16x8_t*)&Bs[(wc + j * 16 + fr) * LDT + ks * 32 + fq * 8];
#pragma unroll
      for (int i = 0; i < 4; i++)
#pragma unroll
        for (int j = 0; j < 4; j++)
          acc[i][j] = __builtin_amdgcn_mfma_f32_16x16x32_bf16(af[i], bfr[j],
                                                              acc[i][j], 0, 0, 0);
    }
  }

  // Epilogue: D col = lane&15, row = (lane>>4)*4 + reg   [m89 layout]
#pragma unroll
  for (int j = 0; j < 4; j++) {
    const int col = n0 + wc + j * 16 + fr;
    const float bc = bias[col];
#pragma unroll
    for (int i = 0; i < 4; i++) {
      const int rowb = m0 + wr + i * 16 + fq * 4;
#pragma unroll
      for (int r4 = 0; r4 < 4; r4++) {
        const size_t off = (size_t)(rowb + r4) * N + col;
        float v = acc[i][j][r4] + bc;
        if (RESID) v += resid[off];
        if (RELU) v = fmaxf(v, 0.0f);
        if (OUTBF16) Cb[off] = f2bf(v);
        else Cf[off] = v;
      }
    }
  }
}

// ---------------------------------------------------------------------------
// BigBird block-sparse attention (bf16 q/k/v in, bf16 ctx out, fp32 math).
// Grid: (B*H*NB, 2), 256 threads. 32 q-rows per block, 5 key-block slots,
// online softmax. ctx may alias qh (disjoint read/write regions per block).
// ---------------------------------------------------------------------------
__global__ __launch_bounds__(256)
void attn_kernel(const unsigned short* __restrict__ qh,
                 const unsigned short* __restrict__ kh,
                 const unsigned short* __restrict__ vh,
                 const int* __restrict__ kbidx,
                 unsigned short* __restrict__ ctx) {
  const int bid = blockIdx.x;
  const int n = bid & 63;
  const int h = (bid >> 6) & 7;
  const int b = bid >> 9;
  const int qr0 = blockIdx.y * 32;
  const int tid = threadIdx.x;

  __shared__ float qs[32][100];
  __shared__ float kv[64][100];
  __shared__ float ss[32][68];
  __shared__ float mrow[32], lrow[32], frow[32];

  // Load Q (32x96): 768 chunks of 4 bf16; 3 per thread
#pragma unroll
  for (int i = 0; i < 3; i++) {
    const int ch = tid + 256 * i;
    const int r = ch / 24, c4 = (ch % 24) * 4;
    const unsigned short* src =
        qh + ((size_t)(b * Ss) + n * 64 + qr0 + r) * Dd + h * HDm + c4;
    ushort4 u = *(const ushort4*)src;
    qs[r][c4 + 0] = bf2f(u.x); qs[r][c4 + 1] = bf2f(u.y);
    qs[r][c4 + 2] = bf2f(u.z); qs[r][c4 + 3] = bf2f(u.w);
  }
  if (tid < 32) { mrow[tid] = -INFINITY; lrow[tid] = 0.0f; }
  float acc[12];
#pragma unroll
  for (int i = 0; i < 12; i++) acc[i] = 0.0f;
  const float scale = 0.1020620726f;  // 1/sqrt(96)
  __syncthreads();

  for (int s = 0; s < 5; s++) {
    const int kb = kbidx[n * 5 + s];
    if (!(s == 0 || kb != 0)) continue;
    const bool diag = (kb == n);

    // K tile (64x96): 1536 chunks, 6 per thread
#pragma unroll
    for (int i = 0; i < 6; i++) {
      const int ch = tid + 256 * i;
      const int r = ch / 24, c4 = (ch % 24) * 4;
      const unsigned short* src =
          kh + ((size_t)(b * Ss) + kb * 64 + r) * Dd + h * HDm + c4;
      ushort4 u = *(const ushort4*)src;
      kv[r][c4 + 0] = bf2f(u.x); kv[r][c4 + 1] = bf2f(u.y);
      kv[r][c4 + 2] = bf2f(u.z); kv[r][c4 + 3] = bf2f(u.w);
    }
    __syncthreads();

    {
      const int r0 = (tid & 15) * 2;
      const int pb = (tid >> 4) * 4;
      float sc[2][4];
#pragma unroll
      for (int i = 0; i < 2; i++)
#pragma unroll
        for (int j = 0; j < 4; j++) sc[i][j] = 0.0f;
      for (int kk = 0; kk < 96; kk += 4) {
        float4 q0 = *(const float4*)&qs[r0][kk];
        float4 q1 = *(const float4*)&qs[r0 + 1][kk];
#pragma unroll
        for (int j = 0; j < 4; j++) {
          float4 kr = *(const float4*)&kv[pb + j][kk];
          sc[0][j] += q0.x * kr.x + q0.y * kr.y + q0.z * kr.z + q0.w * kr.w;
          sc[1][j] += q1.x * kr.x + q1.y * kr.y + q1.z * kr.z + q1.w * kr.w;
        }
      }
#pragma unroll
      for (int i = 0; i < 2; i++)
#pragma unroll
        for (int j = 0; j < 4; j++) {
          float v = sc[i][j] * scale;
          if (diag && (pb + j) > (qr0 + r0 + i)) v = -1e9f;
          ss[r0 + i][pb + j] = v;
        }
    }
    __syncthreads();

    {
      const int r = tid >> 3;
      const int sub = tid & 7;
      float vals[8];
      float mt = -INFINITY;
#pragma unroll
      for (int j = 0; j < 8; j++) {
        vals[j] = ss[r][sub + 8 * j];
        mt = fmaxf(mt, vals[j]);
      }
#pragma unroll
      for (int o = 1; o < 8; o <<= 1) mt = fmaxf(mt, __shfl_xor(mt, o));
      const float mold = mrow[r];
      const float mnew = fmaxf(mold, mt);
      float psum = 0.0f;
#pragma unroll
      for (int j = 0; j < 8; j++) {
        float e = expf(vals[j] - mnew);
        ss[r][sub + 8 * j] = e;
        psum += e;
      }
#pragma unroll
      for (int o = 1; o < 8; o <<= 1) psum += __shfl_xor(psum, o);
      if (sub == 0) {
        const float f = expf(mold - mnew);
        lrow[r] = lrow[r] * f + psum;
        mrow[r] = mnew;
        frow[r] = f;
      }
    }
    __syncthreads();

    // V tile
#pragma unroll
    for (int i = 0; i < 6; i++) {
      const int ch = tid + 256 * i;
      const int r = ch / 24, c4 = (ch % 24) * 4;
      const unsigned short* src =
          vh + ((size_t)(b * Ss) + kb * 64 + r) * Dd + h * HDm + c4;
      ushort4 u = *(const ushort4*)src;
      kv[r][c4 + 0] = bf2f(u.x); kv[r][c4 + 1] = bf2f(u.y);
      kv[r][c4 + 2] = bf2f(u.z); kv[r][c4 + 3] = bf2f(u.w);
    }
    __syncthreads();

    {
      const int r = tid & 31;
      const int d0 = (tid >> 5) * 12;
      const float f = frow[r];
#pragma unroll
      for (int i = 0; i < 12; i++) acc[i] *= f;
      for (int p = 0; p < 64; p++) {
        const float pr = ss[r][p];
        float4 v0 = *(const float4*)&kv[p][d0];
        float4 v1 = *(const float4*)&kv[p][d0 + 4];
        float4 v2 = *(const float4*)&kv[p][d0 + 8];
        acc[0] = fmaf(pr, v0.x, acc[0]);   acc[1] = fmaf(pr, v0.y, acc[1]);
        acc[2] = fmaf(pr, v0.z, acc[2]);   acc[3] = fmaf(pr, v0.w, acc[3]);
        acc[4] = fmaf(pr, v1.x, acc[4]);   acc[5] = fmaf(pr, v1.y, acc[5]);
        acc[6] = fmaf(pr, v1.z, acc[6]);   acc[7] = fmaf(pr, v1.w, acc[7]);
        acc[8] = fmaf(pr, v2.x, acc[8]);   acc[9] = fmaf(pr, v2.y, acc[9]);
        acc[10] = fmaf(pr, v2.z, acc[10]); acc[11] = fmaf(pr, v2.w, acc[11]);
      }
    }
    __syncthreads();
  }

  {
    const int r = tid & 31;
    const int d0 = (tid >> 5) * 12;
    const float inv = 1.0f / lrow[r];
    unsigned short* dst =
        ctx + ((size_t)(b * Ss) + n * 64 + qr0 + r) * Dd + h * HDm + d0;
    ushort4 s0, s1, s2;
    s0.x = f2bf(acc[0] * inv);  s0.y = f2bf(acc[1] * inv);
    s0.z = f2bf(acc[2] * inv);  s0.w = f2bf(acc[3] * inv);
    s1.x = f2bf(acc[4] * inv);  s1.y = f2bf(acc[5] * inv);
    s1.z = f2bf(acc[6] * inv);  s1.w = f2bf(acc[7] * inv);
    s2.x = f2bf(acc[8] * inv);  s2.y = f2bf(acc[9] * inv);
    s2.z = f2bf(acc[10] * inv); s2.w = f2bf(acc[11] * inv);
    *(ushort4*)(dst)     = s0;
    *(ushort4*)(dst + 4) = s1;
    *(ushort4*)(dst + 8) = s2;
  }
}

// ---------------------------------------------------------------------------
// Host launcher.
// ws layout (ushorts): [Wqt|Wkt|Wvt|Wot (589824 each)][W1t 2359296][W2t 2359296]
//   [h 12582912][big 50331648: qh|kh|vh (12582912 each) -> later fbuf 16384x3072]
// Total = 69,992,448 ushorts = 133.5 MiB.
// x1 lives in d_out fp32 (written by Wo-GEMM, LN'd, updated in-place by FFN2).
// ---------------------------------------------------------------------------
extern "C" void kernel_launch(void* const* d_in, const int* in_sizes, int n_in,
                              void* d_out, int out_size, void* d_ws, size_t ws_size,
                              hipStream_t stream) {
  const float* x    = (const float*)d_in[0];
  const float* Wq   = (const float*)d_in[1];
  const float* bq   = (const float*)d_in[2];
  const float* Wk   = (const float*)d_in[3];
  const float* bk   = (const float*)d_in[4];
  const float* Wv   = (const float*)d_in[5];
  const float* bv   = (const float*)d_in[6];
  const float* Wo   = (const float*)d_in[7];
  const float* bo   = (const float*)d_in[8];
  const float* ln_g = (const float*)d_in[9];
  const float* ln_b = (const float*)d_in[10];
  const float* W1   = (const float*)d_in[11];
  const float* b1   = (const float*)d_in[12];
  const float* W2   = (const float*)d_in[13];
  const float* b2   = (const float*)d_in[14];
  const int*   kb   = (const int*)d_in[15];

  float* out = (float*)d_out;
  unsigned short* ws = (unsigned short*)d_ws;

  constexpr size_t WSQ = (size_t)Dd * Dd;           // 589824
  constexpr size_t WSF = (size_t)Dd * DFFc;         // 2359296
  constexpr size_t SZ  = (size_t)MROWS * Dd;        // 12582912
  unsigned short* Wqt = ws;
  unsigned short* Wkt = Wqt + WSQ;
  unsigned short* Wvt = Wkt + WSQ;
  unsigned short* Wot = Wvt + WSQ;
  unsigned short* W1t = Wot + WSQ;
  unsigned short* W2t = W1t + WSF;
  unsigned short* h   = W2t + WSF;
  unsigned short* big = h + SZ;
  unsigned short* qh  = big;
  unsigned short* kh  = big + SZ;
  unsigned short* vh  = big + 2 * SZ;
  unsigned short* ctxb = qh;       // attention writes in place over qh
  unsigned short* fbuf = big;      // FFN intermediate (16384x3072) after attn

  // 0. Weight transpose+cast (bf16 [N][K])
  transpose_cast<<<dim3(Dd / 64, Dd / 64), 256, 0, stream>>>(Wq, Wqt, Dd, Dd);
  transpose_cast<<<dim3(Dd / 64, Dd / 64), 256, 0, stream>>>(Wk, Wkt, Dd, Dd);
  transpose_cast<<<dim3(Dd / 64, Dd / 64), 256, 0, stream>>>(Wv, Wvt, Dd, Dd);
  transpose_cast<<<dim3(Dd / 64, Dd / 64), 256, 0, stream>>>(Wo, Wot, Dd, Dd);
  transpose_cast<<<dim3(DFFc / 64, Dd / 64), 256, 0, stream>>>(W1, W1t, Dd, DFFc);
  transpose_cast<<<dim3(Dd / 64, DFFc / 64), 256, 0, stream>>>(W2, W2t, DFFc, Dd);

  // 1. h = LN(x) -> bf16
  ln_kernel<<<MROWS, 192, 0, stream>>>(x, ln_g, ln_b, h);

  // 2-4. QKV projections (bf16 out)
  bgemm<0, 1, 0><<<dim3(Dd / 128, MROWS / 128), 256, 0, stream>>>(
      h, Wqt, bq, nullptr, nullptr, qh, MROWS, Dd, Dd);
  bgemm<0, 1, 0><<<dim3(Dd / 128, MROWS / 128), 256, 0, stream>>>(
      h, Wkt, bk, nullptr, nullptr, kh, MROWS, Dd, Dd);
  bgemm<0, 1, 0><<<dim3(Dd / 128, MROWS / 128), 256, 0, stream>>>(
      h, Wvt, bv, nullptr, nullptr, vh, MROWS, Dd, Dd);

  // 5. attention (ctx -> qh in place, bf16)
  attn_kernel<<<dim3(Bb * Hh * NBK, 2), 256, 0, stream>>>(qh, kh, vh, kb, ctxb);

  // 6. out = x + ctx @ Wo + bo   (fp32)
  bgemm<0, 0, 1><<<dim3(Dd / 128, MROWS / 128), 256, 0, stream>>>(
      ctxb, Wot, bo, x, out, nullptr, MROWS, Dd, Dd);

  // 7. h = LN(out) -> bf16
  ln_kernel<<<MROWS, 192, 0, stream>>>(out, ln_g, ln_b, h);

  // 8. fbuf = relu(h @ W1 + b1) -> bf16   (16384x3072)
  bgemm<1, 1, 0><<<dim3(DFFc / 128, MROWS / 128), 256, 0, stream>>>(
      h, W1t, b1, nullptr, nullptr, fbuf, MROWS, DFFc, Dd);

  // 9. out += fbuf @ W2 + b2   (fp32, in-place resid)
  bgemm<0, 0, 1><<<dim3(Dd / 128, MROWS / 128), 256, 0, stream>>>(
      fbuf, W2t, b2, out, out, nullptr, MROWS, Dd, DFFc);
}

// Round 6
// 1820.584 us; speedup vs baseline: 1.8987x; 1.0305x over previous
//
#include <hip/hip_runtime.h>
#include <math.h>

// B=4 S=4096 D=768 H=8 BS=64 NB=64 NKB=5 HD=96 DFF=3072
static constexpr int Bb   = 4;
static constexpr int Ss   = 4096;
static constexpr int Dd   = 768;
static constexpr int HDm  = 96;
static constexpr int DFFc = 3072;
static constexpr int MROWS = Bb * Ss;  // 16384
static constexpr int NBK  = 64;
static constexpr int Hh   = 8;
static constexpr int QLD  = 2304;      // fused QKV row stride

typedef float f32x4_t __attribute__((ext_vector_type(4)));
typedef short s16x8_t __attribute__((ext_vector_type(8)));

__device__ __forceinline__ unsigned short f2bf(float f) {
  union { float f; unsigned int u; } c; c.f = f;
  unsigned int u = c.u;
  unsigned int r = (u + 0x7FFFu + ((u >> 16) & 1u)) >> 16;
  return (unsigned short)r;
}
__device__ __forceinline__ float bf2f(unsigned short u) {
  union { unsigned int u; float f; } c; c.u = ((unsigned int)u) << 16;
  return c.f;
}

// ---------------------------------------------------------------------------
// Weight transpose+cast: src fp32 [K][N] -> dst bf16 [N][K]. 64x64 tiles.
// ---------------------------------------------------------------------------
__global__ __launch_bounds__(256)
void transpose_cast(const float* __restrict__ src, unsigned short* __restrict__ dst,
                    int K, int N) {
  __shared__ float t[64][65];
  const int n0 = blockIdx.x * 64, k0 = blockIdx.y * 64;
  const int tid = threadIdx.x;
  {
    const int r = tid >> 2, cs = (tid & 3) * 16;
    const float* sp = src + (size_t)(k0 + r) * N + n0 + cs;
#pragma unroll
    for (int u = 0; u < 4; u++) {
      float4 v = *(const float4*)(sp + u * 4);
      t[r][cs + u * 4 + 0] = v.x; t[r][cs + u * 4 + 1] = v.y;
      t[r][cs + u * 4 + 2] = v.z; t[r][cs + u * 4 + 3] = v.w;
    }
  }
  __syncthreads();
  {
    const int n = tid >> 2, ks = (tid & 3) * 16;
    unsigned short o[16];
#pragma unroll
    for (int j = 0; j < 16; j++) o[j] = f2bf(t[ks + j][n]);
    unsigned short* dp = dst + (size_t)(n0 + n) * K + k0 + ks;
    *(uint4*)(dp)     = *(uint4*)(o);
    *(uint4*)(dp + 8) = *(uint4*)(o + 8);
  }
}

// ---------------------------------------------------------------------------
// LayerNorm: fp32 in, bf16 out. 192 threads/row.
// ---------------------------------------------------------------------------
__global__ __launch_bounds__(192)
void ln_kernel(const float* __restrict__ x, const float* __restrict__ g,
               const float* __restrict__ beta, unsigned short* __restrict__ out) {
  const int row = blockIdx.x;
  const int t = threadIdx.x;
  const float* xr = x + (size_t)row * Dd;
  float4 v = *(const float4*)(xr + t * 4);
  float s  = v.x + v.y + v.z + v.w;
  float sq = v.x * v.x + v.y * v.y + v.z * v.z + v.w * v.w;
#pragma unroll
  for (int o = 32; o; o >>= 1) {
    s  += __shfl_xor(s, o);
    sq += __shfl_xor(sq, o);
  }
  __shared__ float rs[4], rq[4];
  const int w = t >> 6;
  if ((t & 63) == 0) { rs[w] = s; rq[w] = sq; }
  __syncthreads();
  s  = rs[0] + rs[1] + rs[2];
  sq = rq[0] + rq[1] + rq[2];
  const float mean = s * (1.0f / Dd);
  const float var  = sq * (1.0f / Dd) - mean * mean;
  const float rstd = rsqrtf(var + 1e-5f);
  float4 gv = *(const float4*)(g + t * 4);
  float4 bv = *(const float4*)(beta + t * 4);
  ushort4 o;
  o.x = f2bf((v.x - mean) * rstd * gv.x + bv.x);
  o.y = f2bf((v.y - mean) * rstd * gv.y + bv.y);
  o.z = f2bf((v.z - mean) * rstd * gv.z + bv.z);
  o.w = f2bf((v.w - mean) * rstd * gv.w + bv.w);
  *(ushort4*)(out + (size_t)row * Dd + t * 4) = o;
}

// ---------------------------------------------------------------------------
// BF16 MFMA GEMM: C[M,N] = act(A[M,K(lda)] @ Bt[N,K]^T + bias (+ fp32 resid))
// Tile 128x128, BK=64, 256 threads (4 waves 2x2), 64x64/wave.
// Grid: 1D, XCD-bijective swizzle + within-XCD 2D chunking (6 B-panels
// resident in the XCD's 4MB L2, by-mid, bxg-outer). Requires N%768==0-ish:
// GX%6==0, (nwg/GX)%8==0 — true for all shapes here (GY=128).
// Epilogue: per-wave LDS C-staging (stride 76 floats) -> 16B stores.
// SEL3: 3-way bias select for fused QKV (col/768).
// ---------------------------------------------------------------------------
template <int RELU, int OUTBF16, int RESID, int SEL3>
__global__ __launch_bounds__(256)
void bgemm(const unsigned short* __restrict__ A, const unsigned short* __restrict__ Bt,
           const float* __restrict__ b0, const float* __restrict__ b1,
           const float* __restrict__ b2, const float* __restrict__ resid,
           float* __restrict__ Cf, unsigned short* __restrict__ Cb,
           int N, int K, int lda, int GX) {
  constexpr int LDT = 72;
  __shared__ __align__(16) unsigned short As[128 * LDT];
  __shared__ __align__(16) unsigned short Bs[128 * LDT];
  const int tid = threadIdx.x;

  // --- block swizzle: XCD-contiguous, 6-wide bx groups, by-mid ---
  const int nwg = gridDim.x;
  const int GYc = (nwg / GX) >> 3;           // per-XCD y-chunk (=16)
  const int xcd = blockIdx.x & 7;
  const int t   = blockIdx.x >> 3;           // [0, GX*GYc)
  const int bxg = t / (6 * GYc);
  const int rr_ = t - bxg * 6 * GYc;
  const int by  = xcd * GYc + rr_ / 6;
  const int bx  = bxg * 6 + rr_ % 6;
  const int n0 = bx * 128, m0 = by * 128;

  // staging: row = tid>>1 (0..127), half = (tid&1)*32 ushorts
  const int srow = tid >> 1;
  const int shalf = (tid & 1) * 32;
  const unsigned short* Ap = A + (size_t)(m0 + srow) * lda + shalf;
  const unsigned short* Bp = Bt + (size_t)(n0 + srow) * K + shalf;

  const int lane = tid & 63, w = tid >> 6;
  const int wr = (w >> 1) * 64, wc = (w & 1) * 64;
  const int fr = lane & 15, fq = lane >> 4;

  f32x4_t acc[4][4];
#pragma unroll
  for (int i = 0; i < 4; i++)
#pragma unroll
    for (int j = 0; j < 4; j++) acc[i][j] = (f32x4_t)0.0f;

  uint4 ra[4], rb[4];
#pragma unroll
  for (int u = 0; u < 4; u++) {
    ra[u] = *(const uint4*)(Ap + u * 8);
    rb[u] = *(const uint4*)(Bp + u * 8);
  }

  for (int kt = 0; kt < K; kt += 64) {
    __syncthreads();
#pragma unroll
    for (int u = 0; u < 4; u++) {
      *(uint4*)&As[srow * LDT + shalf + u * 8] = ra[u];
      *(uint4*)&Bs[srow * LDT + shalf + u * 8] = rb[u];
    }
    __syncthreads();
    if (kt + 64 < K) {
#pragma unroll
      for (int u = 0; u < 4; u++) {
        ra[u] = *(const uint4*)(Ap + kt + 64 + u * 8);
        rb[u] = *(const uint4*)(Bp + kt + 64 + u * 8);
      }
    }
#pragma unroll
    for (int ks = 0; ks < 2; ks++) {
      s16x8_t af[4], bfr[4];
#pragma unroll
      for (int i = 0; i < 4; i++)
        af[i] = *(const s16x8_t*)&As[(wr + i * 16 + fr) * LDT + ks * 32 + fq * 8];
#pragma unroll
      for (int j = 0; j < 4; j++)
        bfr[j] = *(const s16x8_t*)&Bs[(wc + j * 16 + fr) * LDT + ks * 32 + fq * 8];
#pragma unroll
      for (int i = 0; i < 4; i++)
#pragma unroll
        for (int j = 0; j < 4; j++)
          acc[i][j] = __builtin_amdgcn_mfma_f32_16x16x32_bf16(af[i], bfr[j],
                                                              acc[i][j], 0, 0, 0);
    }
  }

  // ---- Epilogue: stage C through per-wave LDS slab, vectorized stores ----
  __syncthreads();  // all waves done with As/Bs
  constexpr int CLD = 76;                       // floats; 16B-aligned rows, ~2-way banks
  float* cs = (float*)(&As[0]) + w * (16 * CLD);  // 4864B per wave slab

#pragma unroll
  for (int i = 0; i < 4; i++) {
    // scatter acc -> slab (D layout: col=lane&15, row=(lane>>4)*4+reg)
#pragma unroll
    for (int j = 0; j < 4; j++) {
      const int col = n0 + wc + j * 16 + fr;
      float bc;
      if (SEL3)
        bc = col < 768 ? b0[col] : (col < 1536 ? b1[col - 768] : b2[col - 1536]);
      else
        bc = b0[col];
#pragma unroll
      for (int r4 = 0; r4 < 4; r4++) {
        float v = acc[i][j][r4] + bc;
        if (RELU) v = fmaxf(v, 0.0f);
        cs[(fq * 4 + r4) * CLD + j * 16 + fr] = v;
      }
    }
    // per-wave slab: no cross-wave hazard; compiler orders LDS ops in-wave
    if (OUTBF16) {
#pragma unroll
      for (int u = 0; u < 2; u++) {
        const int rr = (lane >> 3) + u * 8;
        const int c0 = (lane & 7) * 8;
        float4 x0 = *(float4*)&cs[rr * CLD + c0];
        float4 x1 = *(float4*)&cs[rr * CLD + c0 + 4];
        unsigned short o[8];
        o[0] = f2bf(x0.x); o[1] = f2bf(x0.y); o[2] = f2bf(x0.z); o[3] = f2bf(x0.w);
        o[4] = f2bf(x1.x); o[5] = f2bf(x1.y); o[6] = f2bf(x1.z); o[7] = f2bf(x1.w);
        *(uint4*)(Cb + (size_t)(m0 + wr + i * 16 + rr) * N + n0 + wc + c0) =
            *(uint4*)o;
      }
    } else {
#pragma unroll
      for (int u = 0; u < 4; u++) {
        const int rr = (lane >> 4) + u * 4;
        const int c0 = (lane & 15) * 4;
        const size_t off = (size_t)(m0 + wr + i * 16 + rr) * N + n0 + wc + c0;
        float4 x = *(float4*)&cs[rr * CLD + c0];
        if (RESID) {
          float4 r = *(const float4*)(resid + off);
          x.x += r.x; x.y += r.y; x.z += r.z; x.w += r.w;
        }
        *(float4*)(Cf + off) = x;
      }
    }
    __syncthreads();  // slab reuse across i (cheap; keeps waves roughly together)
  }
}

// ---------------------------------------------------------------------------
// BigBird block-sparse attention on fused QKV buffer (row stride QLD=2304).
// q at +0, k at +768, v at +1536. ctx written in place over the q section
// (each block reads only its own 32 q-rows first, writes them last).
// Grid: (B*H*NB, 2), 256 threads, online softmax, fp32 math.
// ---------------------------------------------------------------------------
__global__ __launch_bounds__(256)
void attn_kernel(const unsigned short* __restrict__ qkv,
                 const int* __restrict__ kbidx,
                 unsigned short* __restrict__ ctx) {
  const int bid = blockIdx.x;
  const int n = bid & 63;
  const int h = (bid >> 6) & 7;
  const int b = bid >> 9;
  const int qr0 = blockIdx.y * 32;
  const int tid = threadIdx.x;

  __shared__ float qs[32][100];
  __shared__ float kv[64][100];
  __shared__ float ss[32][68];
  __shared__ float mrow[32], lrow[32], frow[32];

  // Load Q (32x96)
#pragma unroll
  for (int i = 0; i < 3; i++) {
    const int ch = tid + 256 * i;
    const int r = ch / 24, c4 = (ch % 24) * 4;
    const unsigned short* src =
        qkv + ((size_t)(b * Ss) + n * 64 + qr0 + r) * QLD + h * HDm + c4;
    ushort4 u = *(const ushort4*)src;
    qs[r][c4 + 0] = bf2f(u.x); qs[r][c4 + 1] = bf2f(u.y);
    qs[r][c4 + 2] = bf2f(u.z); qs[r][c4 + 3] = bf2f(u.w);
  }
  if (tid < 32) { mrow[tid] = -INFINITY; lrow[tid] = 0.0f; }
  float acc[12];
#pragma unroll
  for (int i = 0; i < 12; i++) acc[i] = 0.0f;
  const float scale = 0.1020620726f;  // 1/sqrt(96)
  __syncthreads();

  for (int s = 0; s < 5; s++) {
    const int kb = kbidx[n * 5 + s];
    if (!(s == 0 || kb != 0)) continue;
    const bool diag = (kb == n);

    // K tile (64x96)
#pragma unroll
    for (int i = 0; i < 6; i++) {
      const int ch = tid + 256 * i;
      const int r = ch / 24, c4 = (ch % 24) * 4;
      const unsigned short* src =
          qkv + 768 + ((size_t)(b * Ss) + kb * 64 + r) * QLD + h * HDm + c4;
      ushort4 u = *(const ushort4*)src;
      kv[r][c4 + 0] = bf2f(u.x); kv[r][c4 + 1] = bf2f(u.y);
      kv[r][c4 + 2] = bf2f(u.z); kv[r][c4 + 3] = bf2f(u.w);
    }
    __syncthreads();

    {
      const int r0 = (tid & 15) * 2;
      const int pb = (tid >> 4) * 4;
      float sc[2][4];
#pragma unroll
      for (int i = 0; i < 2; i++)
#pragma unroll
        for (int j = 0; j < 4; j++) sc[i][j] = 0.0f;
      for (int kk = 0; kk < 96; kk += 4) {
        float4 q0 = *(const float4*)&qs[r0][kk];
        float4 q1 = *(const float4*)&qs[r0 + 1][kk];
#pragma unroll
        for (int j = 0; j < 4; j++) {
          float4 kr = *(const float4*)&kv[pb + j][kk];
          sc[0][j] += q0.x * kr.x + q0.y * kr.y + q0.z * kr.z + q0.w * kr.w;
          sc[1][j] += q1.x * kr.x + q1.y * kr.y + q1.z * kr.z + q1.w * kr.w;
        }
      }
#pragma unroll
      for (int i = 0; i < 2; i++)
#pragma unroll
        for (int j = 0; j < 4; j++) {
          float v = sc[i][j] * scale;
          if (diag && (pb + j) > (qr0 + r0 + i)) v = -1e9f;
          ss[r0 + i][pb + j] = v;
        }
    }
    __syncthreads();

    {
      const int r = tid >> 3;
      const int sub = tid & 7;
      float vals[8];
      float mt = -INFINITY;
#pragma unroll
      for (int j = 0; j < 8; j++) {
        vals[j] = ss[r][sub + 8 * j];
        mt = fmaxf(mt, vals[j]);
      }
#pragma unroll
      for (int o = 1; o < 8; o <<= 1) mt = fmaxf(mt, __shfl_xor(mt, o));
      const float mold = mrow[r];
      const float mnew = fmaxf(mold, mt);
      float psum = 0.0f;
#pragma unroll
      for (int j = 0; j < 8; j++) {
        float e = expf(vals[j] - mnew);
        ss[r][sub + 8 * j] = e;
        psum += e;
      }
#pragma unroll
      for (int o = 1; o < 8; o <<= 1) psum += __shfl_xor(psum, o);
      if (sub == 0) {
        const float f = expf(mold - mnew);
        lrow[r] = lrow[r] * f + psum;
        mrow[r] = mnew;
        frow[r] = f;
      }
    }
    __syncthreads();

    // V tile
#pragma unroll
    for (int i = 0; i < 6; i++) {
      const int ch = tid + 256 * i;
      const int r = ch / 24, c4 = (ch % 24) * 4;
      const unsigned short* src =
          qkv + 1536 + ((size_t)(b * Ss) + kb * 64 + r) * QLD + h * HDm + c4;
      ushort4 u = *(const ushort4*)src;
      kv[r][c4 + 0] = bf2f(u.x); kv[r][c4 + 1] = bf2f(u.y);
      kv[r][c4 + 2] = bf2f(u.z); kv[r][c4 + 3] = bf2f(u.w);
    }
    __syncthreads();

    {
      const int r = tid & 31;
      const int d0 = (tid >> 5) * 12;
      const float f = frow[r];
#pragma unroll
      for (int i = 0; i < 12; i++) acc[i] *= f;
      for (int p = 0; p < 64; p++) {
        const float pr = ss[r][p];
        float4 v0 = *(const float4*)&kv[p][d0];
        float4 v1 = *(const float4*)&kv[p][d0 + 4];
        float4 v2 = *(const float4*)&kv[p][d0 + 8];
        acc[0] = fmaf(pr, v0.x, acc[0]);   acc[1] = fmaf(pr, v0.y, acc[1]);
        acc[2] = fmaf(pr, v0.z, acc[2]);   acc[3] = fmaf(pr, v0.w, acc[3]);
        acc[4] = fmaf(pr, v1.x, acc[4]);   acc[5] = fmaf(pr, v1.y, acc[5]);
        acc[6] = fmaf(pr, v1.z, acc[6]);   acc[7] = fmaf(pr, v1.w, acc[7]);
        acc[8] = fmaf(pr, v2.x, acc[8]);   acc[9] = fmaf(pr, v2.y, acc[9]);
        acc[10] = fmaf(pr, v2.z, acc[10]); acc[11] = fmaf(pr, v2.w, acc[11]);
      }
    }
    __syncthreads();
  }

  {
    const int r = tid & 31;
    const int d0 = (tid >> 5) * 12;
    const float inv = 1.0f / lrow[r];
    unsigned short* dst =
        ctx + ((size_t)(b * Ss) + n * 64 + qr0 + r) * QLD + h * HDm + d0;
    ushort4 s0, s1, s2;
    s0.x = f2bf(acc[0] * inv);  s0.y = f2bf(acc[1] * inv);
    s0.z = f2bf(acc[2] * inv);  s0.w = f2bf(acc[3] * inv);
    s1.x = f2bf(acc[4] * inv);  s1.y = f2bf(acc[5] * inv);
    s1.z = f2bf(acc[6] * inv);  s1.w = f2bf(acc[7] * inv);
    s2.x = f2bf(acc[8] * inv);  s2.y = f2bf(acc[9] * inv);
    s2.z = f2bf(acc[10] * inv); s2.w = f2bf(acc[11] * inv);
    *(ushort4*)(dst)     = s0;
    *(ushort4*)(dst + 4) = s1;
    *(ushort4*)(dst + 8) = s2;
  }
}

// ---------------------------------------------------------------------------
// Host launcher. ws layout (ushorts), total 69,992,448 (133.5 MiB):
//   WqkvT [2304][768] @0          (Q rows 0-767, K 768-1535, V 1536-2303)
//   Wot   [768][768]  @1,769,472
//   W1t   [3072][768] @2,359,296
//   W2t   [768][3072] @4,718,592
//   h     [16384][768] @7,077,888
//   pool  @19,660,800: fused QKV [16384][2304] (72MB), later fbuf
//         [16384][3072] (96MB) overlapping.
// x1 lives in d_out fp32 (Wo-GEMM writes, LN reads, FFN2 read+overwrites).
// ---------------------------------------------------------------------------
extern "C" void kernel_launch(void* const* d_in, const int* in_sizes, int n_in,
                              void* d_out, int out_size, void* d_ws, size_t ws_size,
                              hipStream_t stream) {
  const float* x    = (const float*)d_in[0];
  const float* Wq   = (const float*)d_in[1];
  const float* bq   = (const float*)d_in[2];
  const float* Wk   = (const float*)d_in[3];
  const float* bk   = (const float*)d_in[4];
  const float* Wv   = (const float*)d_in[5];
  const float* bv   = (const float*)d_in[6];
  const float* Wo   = (const float*)d_in[7];
  const float* bo   = (const float*)d_in[8];
  const float* ln_g = (const float*)d_in[9];
  const float* ln_b = (const float*)d_in[10];
  const float* W1   = (const float*)d_in[11];
  const float* b1   = (const float*)d_in[12];
  const float* W2   = (const float*)d_in[13];
  const float* b2   = (const float*)d_in[14];
  const int*   kb   = (const int*)d_in[15];

  float* out = (float*)d_out;
  unsigned short* ws = (unsigned short*)d_ws;

  constexpr size_t WSQ = (size_t)Dd * Dd;           // 589824
  unsigned short* WqkvT = ws;                       // 3*WSQ
  unsigned short* Wot   = WqkvT + 3 * WSQ;
  unsigned short* W1t   = Wot + WSQ;
  unsigned short* W2t   = W1t + (size_t)Dd * DFFc;
  unsigned short* h     = W2t + (size_t)Dd * DFFc;
  unsigned short* pool  = h + (size_t)MROWS * Dd;
  unsigned short* fused = pool;                     // [MROWS][2304]
  unsigned short* fbuf  = pool;                     // [MROWS][3072] (after attn)

  // 0. Weight transpose+cast (bf16 [N][K]); QKV concatenated row-wise.
  transpose_cast<<<dim3(12, 12), 256, 0, stream>>>(Wq, WqkvT,           Dd, Dd);
  transpose_cast<<<dim3(12, 12), 256, 0, stream>>>(Wk, WqkvT + WSQ,     Dd, Dd);
  transpose_cast<<<dim3(12, 12), 256, 0, stream>>>(Wv, WqkvT + 2 * WSQ, Dd, Dd);
  transpose_cast<<<dim3(12, 12), 256, 0, stream>>>(Wo, Wot,             Dd, Dd);
  transpose_cast<<<dim3(48, 12), 256, 0, stream>>>(W1, W1t, Dd, DFFc);
  transpose_cast<<<dim3(12, 48), 256, 0, stream>>>(W2, W2t, DFFc, Dd);

  // 1. h = LN(x) -> bf16
  ln_kernel<<<MROWS, 192, 0, stream>>>(x, ln_g, ln_b, h);

  // 2. fused QKV: [M,2304] = h @ WqkvT^T  (bias 3-way select)
  bgemm<0, 1, 0, 1><<<2304, 256, 0, stream>>>(
      h, WqkvT, bq, bk, bv, nullptr, nullptr, fused, QLD, Dd, Dd, 18);

  // 3. attention (ctx in place over q-section of fused)
  attn_kernel<<<dim3(Bb * Hh * NBK, 2), 256, 0, stream>>>(fused, kb, fused);

  // 4. out = x + ctx @ Wo + bo   (fp32; A = fused q-section, lda=2304)
  bgemm<0, 0, 1, 0><<<768, 256, 0, stream>>>(
      fused, Wot, bo, nullptr, nullptr, x, out, nullptr, Dd, Dd, QLD, 6);

  // 5. h = LN(out) -> bf16
  ln_kernel<<<MROWS, 192, 0, stream>>>(out, ln_g, ln_b, h);

  // 6. fbuf = relu(h @ W1 + b1) -> bf16   [16384][3072]
  bgemm<1, 1, 0, 0><<<3072, 256, 0, stream>>>(
      h, W1t, b1, nullptr, nullptr, nullptr, nullptr, fbuf, DFFc, Dd, Dd, 24);

  // 7. out += fbuf @ W2 + b2   (fp32, in-place resid)
  bgemm<0, 0, 1, 0><<<768, 256, 0, stream>>>(
      fbuf, W2t, b2, nullptr, nullptr, out, out, nullptr, Dd, DFFc, DFFc, 6);
}

// Round 7
// 1475.577 us; speedup vs baseline: 2.3426x; 1.2338x over previous
//
#include <hip/hip_runtime.h>
#include <math.h>

// B=4 S=4096 D=768 H=8 BS=64 NB=64 NKB=5 HD=96 DFF=3072
static constexpr int Bb   = 4;
static constexpr int Ss   = 4096;
static constexpr int Dd   = 768;
static constexpr int HDm  = 96;
static constexpr int DFFc = 3072;
static constexpr int MROWS = Bb * Ss;  // 16384
static constexpr int NBK  = 64;
static constexpr int Hh   = 8;
static constexpr int QLD  = 2304;      // fused QKV row stride

typedef float f32x4_t __attribute__((ext_vector_type(4)));
typedef short s16x8_t __attribute__((ext_vector_type(8)));

__device__ __forceinline__ unsigned short f2bf(float f) {
  union { float f; unsigned int u; } c; c.f = f;
  unsigned int u = c.u;
  unsigned int r = (u + 0x7FFFu + ((u >> 16) & 1u)) >> 16;
  return (unsigned short)r;
}
__device__ __forceinline__ float bf2f(unsigned short u) {
  union { unsigned int u; float f; } c; c.u = ((unsigned int)u) << 16;
  return c.f;
}

// ---------------------------------------------------------------------------
// Weight transpose+cast: src fp32 [K][N] -> dst bf16 [N][K]. 64x64 tiles.
// ---------------------------------------------------------------------------
__global__ __launch_bounds__(256)
void transpose_cast(const float* __restrict__ src, unsigned short* __restrict__ dst,
                    int K, int N) {
  __shared__ float t[64][65];
  const int n0 = blockIdx.x * 64, k0 = blockIdx.y * 64;
  const int tid = threadIdx.x;
  {
    const int r = tid >> 2, cs = (tid & 3) * 16;
    const float* sp = src + (size_t)(k0 + r) * N + n0 + cs;
#pragma unroll
    for (int u = 0; u < 4; u++) {
      float4 v = *(const float4*)(sp + u * 4);
      t[r][cs + u * 4 + 0] = v.x; t[r][cs + u * 4 + 1] = v.y;
      t[r][cs + u * 4 + 2] = v.z; t[r][cs + u * 4 + 3] = v.w;
    }
  }
  __syncthreads();
  {
    const int n = tid >> 2, ks = (tid & 3) * 16;
    unsigned short o[16];
#pragma unroll
    for (int j = 0; j < 16; j++) o[j] = f2bf(t[ks + j][n]);
    unsigned short* dp = dst + (size_t)(n0 + n) * K + k0 + ks;
    *(uint4*)(dp)     = *(uint4*)(o);
    *(uint4*)(dp + 8) = *(uint4*)(o + 8);
  }
}

// ---------------------------------------------------------------------------
// LayerNorm: fp32 in, bf16 out. 192 threads/row.
// ---------------------------------------------------------------------------
__global__ __launch_bounds__(192)
void ln_kernel(const float* __restrict__ x, const float* __restrict__ g,
               const float* __restrict__ beta, unsigned short* __restrict__ out) {
  const int row = blockIdx.x;
  const int t = threadIdx.x;
  const float* xr = x + (size_t)row * Dd;
  float4 v = *(const float4*)(xr + t * 4);
  float s  = v.x + v.y + v.z + v.w;
  float sq = v.x * v.x + v.y * v.y + v.z * v.z + v.w * v.w;
#pragma unroll
  for (int o = 32; o; o >>= 1) {
    s  += __shfl_xor(s, o);
    sq += __shfl_xor(sq, o);
  }
  __shared__ float rs[4], rq[4];
  const int w = t >> 6;
  if ((t & 63) == 0) { rs[w] = s; rq[w] = sq; }
  __syncthreads();
  s  = rs[0] + rs[1] + rs[2];
  sq = rq[0] + rq[1] + rq[2];
  const float mean = s * (1.0f / Dd);
  const float var  = sq * (1.0f / Dd) - mean * mean;
  const float rstd = rsqrtf(var + 1e-5f);
  float4 gv = *(const float4*)(g + t * 4);
  float4 bv = *(const float4*)(beta + t * 4);
  ushort4 o;
  o.x = f2bf((v.x - mean) * rstd * gv.x + bv.x);
  o.y = f2bf((v.y - mean) * rstd * gv.y + bv.y);
  o.z = f2bf((v.z - mean) * rstd * gv.z + bv.z);
  o.w = f2bf((v.w - mean) * rstd * gv.w + bv.w);
  *(ushort4*)(out + (size_t)row * Dd + t * 4) = o;
}

// ---------------------------------------------------------------------------
// BF16 MFMA GEMM: C[M,N] = act(A[M,K(lda)] @ Bt[N,K]^T + bias (+ fp32 resid))
// Tile 128x128, BK=64, 256 threads (4 waves 2x2), 64x64/wave.
// Grid: 1D, XCD-bijective swizzle + within-XCD 2D chunking.
// Epilogue: per-wave LDS C-staging -> 16B stores.
// ---------------------------------------------------------------------------
template <int RELU, int OUTBF16, int RESID, int SEL3>
__global__ __launch_bounds__(256)
void bgemm(const unsigned short* __restrict__ A, const unsigned short* __restrict__ Bt,
           const float* __restrict__ b0, const float* __restrict__ b1,
           const float* __restrict__ b2, const float* __restrict__ resid,
           float* __restrict__ Cf, unsigned short* __restrict__ Cb,
           int N, int K, int lda, int GX) {
  constexpr int LDT = 72;
  __shared__ __align__(16) unsigned short As[128 * LDT];
  __shared__ __align__(16) unsigned short Bs[128 * LDT];
  const int tid = threadIdx.x;

  // --- block swizzle: XCD-contiguous, 6-wide bx groups, by-mid ---
  const int nwg = gridDim.x;
  const int GYc = (nwg / GX) >> 3;           // per-XCD y-chunk
  const int xcd = blockIdx.x & 7;
  const int t   = blockIdx.x >> 3;
  const int bxg = t / (6 * GYc);
  const int rr_ = t - bxg * 6 * GYc;
  const int by  = xcd * GYc + rr_ / 6;
  const int bx  = bxg * 6 + rr_ % 6;
  const int n0 = bx * 128, m0 = by * 128;

  const int srow = tid >> 1;
  const int shalf = (tid & 1) * 32;
  const unsigned short* Ap = A + (size_t)(m0 + srow) * lda + shalf;
  const unsigned short* Bp = Bt + (size_t)(n0 + srow) * K + shalf;

  const int lane = tid & 63, w = tid >> 6;
  const int wr = (w >> 1) * 64, wc = (w & 1) * 64;
  const int fr = lane & 15, fq = lane >> 4;

  f32x4_t acc[4][4];
#pragma unroll
  for (int i = 0; i < 4; i++)
#pragma unroll
    for (int j = 0; j < 4; j++) acc[i][j] = (f32x4_t)0.0f;

  uint4 ra[4], rb[4];
#pragma unroll
  for (int u = 0; u < 4; u++) {
    ra[u] = *(const uint4*)(Ap + u * 8);
    rb[u] = *(const uint4*)(Bp + u * 8);
  }

  for (int kt = 0; kt < K; kt += 64) {
    __syncthreads();
#pragma unroll
    for (int u = 0; u < 4; u++) {
      *(uint4*)&As[srow * LDT + shalf + u * 8] = ra[u];
      *(uint4*)&Bs[srow * LDT + shalf + u * 8] = rb[u];
    }
    __syncthreads();
    if (kt + 64 < K) {
#pragma unroll
      for (int u = 0; u < 4; u++) {
        ra[u] = *(const uint4*)(Ap + kt + 64 + u * 8);
        rb[u] = *(const uint4*)(Bp + kt + 64 + u * 8);
      }
    }
#pragma unroll
    for (int ks = 0; ks < 2; ks++) {
      s16x8_t af[4], bfr[4];
#pragma unroll
      for (int i = 0; i < 4; i++)
        af[i] = *(const s16x8_t*)&As[(wr + i * 16 + fr) * LDT + ks * 32 + fq * 8];
#pragma unroll
      for (int j = 0; j < 4; j++)
        bfr[j] = *(const s16x8_t*)&Bs[(wc + j * 16 + fr) * LDT + ks * 32 + fq * 8];
#pragma unroll
      for (int i = 0; i < 4; i++)
#pragma unroll
        for (int j = 0; j < 4; j++)
          acc[i][j] = __builtin_amdgcn_mfma_f32_16x16x32_bf16(af[i], bfr[j],
                                                              acc[i][j], 0, 0, 0);
    }
  }

  // ---- Epilogue: stage C through per-wave LDS slab, vectorized stores ----
  __syncthreads();
  constexpr int CLD = 76;
  float* cs = (float*)(&As[0]) + w * (16 * CLD);

#pragma unroll
  for (int i = 0; i < 4; i++) {
#pragma unroll
    for (int j = 0; j < 4; j++) {
      const int col = n0 + wc + j * 16 + fr;
      float bc;
      if (SEL3)
        bc = col < 768 ? b0[col] : (col < 1536 ? b1[col - 768] : b2[col - 1536]);
      else
        bc = b0[col];
#pragma unroll
      for (int r4 = 0; r4 < 4; r4++) {
        float v = acc[i][j][r4] + bc;
        if (RELU) v = fmaxf(v, 0.0f);
        cs[(fq * 4 + r4) * CLD + j * 16 + fr] = v;
      }
    }
    if (OUTBF16) {
#pragma unroll
      for (int u = 0; u < 2; u++) {
        const int rr = (lane >> 3) + u * 8;
        const int c0 = (lane & 7) * 8;
        float4 x0 = *(float4*)&cs[rr * CLD + c0];
        float4 x1 = *(float4*)&cs[rr * CLD + c0 + 4];
        unsigned short o[8];
        o[0] = f2bf(x0.x); o[1] = f2bf(x0.y); o[2] = f2bf(x0.z); o[3] = f2bf(x0.w);
        o[4] = f2bf(x1.x); o[5] = f2bf(x1.y); o[6] = f2bf(x1.z); o[7] = f2bf(x1.w);
        *(uint4*)(Cb + (size_t)(m0 + wr + i * 16 + rr) * N + n0 + wc + c0) =
            *(uint4*)o;
      }
    } else {
#pragma unroll
      for (int u = 0; u < 4; u++) {
        const int rr = (lane >> 4) + u * 4;
        const int c0 = (lane & 15) * 4;
        const size_t off = (size_t)(m0 + wr + i * 16 + rr) * N + n0 + wc + c0;
        float4 x = *(float4*)&cs[rr * CLD + c0];
        if (RESID) {
          float4 r = *(const float4*)(resid + off);
          x.x += r.x; x.y += r.y; x.z += r.z; x.w += r.w;
        }
        *(float4*)(Cf + off) = x;
      }
    }
    __syncthreads();
  }
}

// ---------------------------------------------------------------------------
// BigBird block-sparse attention, MFMA version.
// One block per (b,h,n); 4 waves; wave w owns q-rows [w*16, w*16+16).
// Q -> registers (A-frags, reused over slots). Per slot: K staged [64][104],
// V staged transposed Vt[96][72]; S = mfma(Q,K); in-register online softmax
// on C-frags (row = (lane>>4)*4+reg); P -> per-wave LDS strip (bf16) ->
// A-frags for PV; O accumulated in C-frags (row map matches S).
// ctx aliases q-section of fused: block reads its own q-rows (regs, start)
// and writes the same rows/cols at the end; all other accesses are k/v
// sections or other h columns -> disjoint.
// ---------------------------------------------------------------------------
__global__ __launch_bounds__(256)
void attn_mfma(const unsigned short* __restrict__ qkv,
               const int* __restrict__ kbidx,
               unsigned short* __restrict__ ctx) {
  const int bid = blockIdx.x;
  const int n = bid & 63;
  const int h = (bid >> 6) & 7;
  const int b = bid >> 9;
  const int tid = threadIdx.x;
  const int w = tid >> 6, lane = tid & 63;
  const int fr = lane & 15, fq = lane >> 4;

  __shared__ __align__(16) unsigned short Ks[64][104];  // keys x dims (208B rows)
  __shared__ __align__(16) unsigned short Vt[96][72];   // dims x keys (144B rows)
  __shared__ __align__(16) unsigned short Ps[64][72];   // qrows x keys (144B rows)

  // Q A-frags: lane holds Q[w*16+fr][kq*32+fq*8 .. +8)
  s16x8_t qa[3];
  {
    const unsigned short* qrow =
        qkv + ((size_t)(b * Ss) + n * 64 + w * 16 + fr) * QLD + h * HDm;
#pragma unroll
    for (int kq = 0; kq < 3; kq++)
      qa[kq] = *(const s16x8_t*)(qrow + kq * 32 + fq * 8);
  }

  f32x4_t o_acc[6];
#pragma unroll
  for (int dt = 0; dt < 6; dt++) o_acc[dt] = (f32x4_t)0.0f;
  float m_run[4] = {-1e30f, -1e30f, -1e30f, -1e30f};
  float l_run[4] = {0.0f, 0.0f, 0.0f, 0.0f};
  const float scale = 0.1020620726f;  // 1/sqrt(96)

  for (int s = 0; s < 5; s++) {
    const int kb = kbidx[n * 5 + s];
    if (!(s == 0 || kb != 0)) continue;  // invalid slot (uniform)
    const bool diag = (kb == n);

    __syncthreads();  // previous slot's LDS reads complete
    // --- stage K tile [64][96] (natural layout, coalesced chunks) ---
    {
      const unsigned short* kbase =
          qkv + 768 + ((size_t)(b * Ss) + kb * 64) * QLD + h * HDm;
#pragma unroll
      for (int u = 0; u < 3; u++) {
        const int c = tid + 256 * u;         // 0..767
        const int row = c / 12, d0 = (c % 12) * 8;
        *(uint4*)&Ks[row][d0] = *(const uint4*)(kbase + (size_t)row * QLD + d0);
      }
    }
    // --- stage V transposed: wave w handles dims [w*24, w*24+24), key=lane ---
    {
      const unsigned short* vbase =
          qkv + 1536 + ((size_t)(b * Ss) + kb * 64 + lane) * QLD + h * HDm + w * 24;
      unsigned short va[24];
      *(uint4*)&va[0]  = *(const uint4*)(vbase);
      *(uint4*)&va[8]  = *(const uint4*)(vbase + 8);
      *(uint4*)&va[16] = *(const uint4*)(vbase + 16);
#pragma unroll
      for (int j = 0; j < 24; j++) Vt[w * 24 + j][lane] = va[j];
    }
    __syncthreads();  // staging visible

    // --- QK^T: wave strip 16 rows x 64 keys (4 col-tiles x 3 K-mfma) ---
    f32x4_t sf[4];
#pragma unroll
    for (int jt = 0; jt < 4; jt++) {
      sf[jt] = (f32x4_t)0.0f;
#pragma unroll
      for (int kq = 0; kq < 3; kq++) {
        s16x8_t kf = *(const s16x8_t*)&Ks[jt * 16 + fr][kq * 32 + fq * 8];
        sf[jt] = __builtin_amdgcn_mfma_f32_16x16x32_bf16(qa[kq], kf, sf[jt], 0, 0, 0);
      }
    }

    // --- online softmax on C-frags: col=jt*16+fr, row=w*16+fq*4+r ---
    float p[4][4];
    float mt[4] = {-1e30f, -1e30f, -1e30f, -1e30f};
#pragma unroll
    for (int jt = 0; jt < 4; jt++)
#pragma unroll
      for (int r = 0; r < 4; r++) {
        float v = sf[jt][r] * scale;
        if (diag && (jt * 16 + fr) > (w * 16 + fq * 4 + r)) v = -1e9f;
        p[jt][r] = v;
        mt[r] = fmaxf(mt[r], v);
      }
#pragma unroll
    for (int off = 1; off < 16; off <<= 1)
#pragma unroll
      for (int r = 0; r < 4; r++) mt[r] = fmaxf(mt[r], __shfl_xor(mt[r], off));
    float fsc[4], rs[4];
#pragma unroll
    for (int r = 0; r < 4; r++) {
      const float mnew = fmaxf(m_run[r], mt[r]);
      fsc[r] = __expf(m_run[r] - mnew);
      m_run[r] = mnew;
      float s0 = 0.0f;
#pragma unroll
      for (int jt = 0; jt < 4; jt++) {
        p[jt][r] = __expf(p[jt][r] - mnew);
        s0 += p[jt][r];
      }
      rs[r] = s0;
    }
#pragma unroll
    for (int off = 1; off < 16; off <<= 1)
#pragma unroll
      for (int r = 0; r < 4; r++) rs[r] += __shfl_xor(rs[r], off);
#pragma unroll
    for (int r = 0; r < 4; r++) l_run[r] = l_run[r] * fsc[r] + rs[r];
#pragma unroll
    for (int dt = 0; dt < 6; dt++)
#pragma unroll
      for (int r = 0; r < 4; r++) o_acc[dt][r] *= fsc[r];

    // --- P -> per-wave LDS strip (bf16); no cross-wave sharing ---
#pragma unroll
    for (int jt = 0; jt < 4; jt++)
#pragma unroll
      for (int r = 0; r < 4; r++)
        Ps[w * 16 + fq * 4 + r][jt * 16 + fr] = f2bf(p[jt][r]);

    // --- PV: O[16x96] += P[16x64] @ V[64x96] ---
    s16x8_t pf[2];
#pragma unroll
    for (int k2 = 0; k2 < 2; k2++)
      pf[k2] = *(const s16x8_t*)&Ps[w * 16 + fr][k2 * 32 + fq * 8];
#pragma unroll
    for (int dt = 0; dt < 6; dt++)
#pragma unroll
      for (int k2 = 0; k2 < 2; k2++) {
        s16x8_t vf = *(const s16x8_t*)&Vt[dt * 16 + fr][k2 * 32 + fq * 8];
        o_acc[dt] = __builtin_amdgcn_mfma_f32_16x16x32_bf16(pf[k2], vf, o_acc[dt], 0, 0, 0);
      }
  }

  // --- epilogue: ctx = O / l ---
#pragma unroll
  for (int r = 0; r < 4; r++) {
    const float inv = 1.0f / l_run[r];
    unsigned short* dst =
        ctx + ((size_t)(b * Ss) + n * 64 + w * 16 + fq * 4 + r) * QLD + h * HDm;
#pragma unroll
    for (int dt = 0; dt < 6; dt++)
      dst[dt * 16 + fr] = f2bf(o_acc[dt][r] * inv);
  }
}

// ---------------------------------------------------------------------------
// Host launcher. ws layout (ushorts), total 69,992,448 (133.5 MiB):
//   WqkvT [2304][768] | Wot [768][768] | W1t [3072][768] | W2t [768][3072]
//   h [16384][768] | pool: fused QKV [16384][2304] -> later fbuf [16384][3072]
// x1 lives in d_out fp32.
// ---------------------------------------------------------------------------
extern "C" void kernel_launch(void* const* d_in, const int* in_sizes, int n_in,
                              void* d_out, int out_size, void* d_ws, size_t ws_size,
                              hipStream_t stream) {
  const float* x    = (const float*)d_in[0];
  const float* Wq   = (const float*)d_in[1];
  const float* bq   = (const float*)d_in[2];
  const float* Wk   = (const float*)d_in[3];
  const float* bk   = (const float*)d_in[4];
  const float* Wv   = (const float*)d_in[5];
  const float* bv   = (const float*)d_in[6];
  const float* Wo   = (const float*)d_in[7];
  const float* bo   = (const float*)d_in[8];
  const float* ln_g = (const float*)d_in[9];
  const float* ln_b = (const float*)d_in[10];
  const float* W1   = (const float*)d_in[11];
  const float* b1   = (const float*)d_in[12];
  const float* W2   = (const float*)d_in[13];
  const float* b2   = (const float*)d_in[14];
  const int*   kb   = (const int*)d_in[15];

  float* out = (float*)d_out;
  unsigned short* ws = (unsigned short*)d_ws;

  constexpr size_t WSQ = (size_t)Dd * Dd;
  unsigned short* WqkvT = ws;
  unsigned short* Wot   = WqkvT + 3 * WSQ;
  unsigned short* W1t   = Wot + WSQ;
  unsigned short* W2t   = W1t + (size_t)Dd * DFFc;
  unsigned short* h     = W2t + (size_t)Dd * DFFc;
  unsigned short* pool  = h + (size_t)MROWS * Dd;
  unsigned short* fused = pool;                     // [MROWS][2304]
  unsigned short* fbuf  = pool;                     // [MROWS][3072] (after attn)

  // 0. Weight transpose+cast (bf16 [N][K]); QKV concatenated row-wise.
  transpose_cast<<<dim3(12, 12), 256, 0, stream>>>(Wq, WqkvT,           Dd, Dd);
  transpose_cast<<<dim3(12, 12), 256, 0, stream>>>(Wk, WqkvT + WSQ,     Dd, Dd);
  transpose_cast<<<dim3(12, 12), 256, 0, stream>>>(Wv, WqkvT + 2 * WSQ, Dd, Dd);
  transpose_cast<<<dim3(12, 12), 256, 0, stream>>>(Wo, Wot,             Dd, Dd);
  transpose_cast<<<dim3(48, 12), 256, 0, stream>>>(W1, W1t, Dd, DFFc);
  transpose_cast<<<dim3(12, 48), 256, 0, stream>>>(W2, W2t, DFFc, Dd);

  // 1. h = LN(x) -> bf16
  ln_kernel<<<MROWS, 192, 0, stream>>>(x, ln_g, ln_b, h);

  // 2. fused QKV: [M,2304] = h @ WqkvT^T  (bias 3-way select)
  bgemm<0, 1, 0, 1><<<2304, 256, 0, stream>>>(
      h, WqkvT, bq, bk, bv, nullptr, nullptr, fused, QLD, Dd, Dd, 18);

  // 3. attention (MFMA; ctx in place over q-section of fused)
  attn_mfma<<<Bb * Hh * NBK, 256, 0, stream>>>(fused, kb, fused);

  // 4. out = x + ctx @ Wo + bo   (fp32; A = fused q-section, lda=2304)
  bgemm<0, 0, 1, 0><<<768, 256, 0, stream>>>(
      fused, Wot, bo, nullptr, nullptr, x, out, nullptr, Dd, Dd, QLD, 6);

  // 5. h = LN(out) -> bf16
  ln_kernel<<<MROWS, 192, 0, stream>>>(out, ln_g, ln_b, h);

  // 6. fbuf = relu(h @ W1 + b1) -> bf16   [16384][3072]
  bgemm<1, 1, 0, 0><<<3072, 256, 0, stream>>>(
      h, W1t, b1, nullptr, nullptr, nullptr, nullptr, fbuf, DFFc, Dd, Dd, 24);

  // 7. out += fbuf @ W2 + b2   (fp32, in-place resid)
  bgemm<0, 0, 1, 0><<<768, 256, 0, stream>>>(
      fbuf, W2t, b2, nullptr, nullptr, out, out, nullptr, Dd, DFFc, DFFc, 6);
}

// Round 8
// 567.056 us; speedup vs baseline: 6.0959x; 2.6022x over previous
//
#include <hip/hip_runtime.h>
#include <math.h>

// B=4 S=4096 D=768 H=8 BS=64 NB=64 NKB=5 HD=96 DFF=3072
static constexpr int Bb   = 4;
static constexpr int Ss   = 4096;
static constexpr int Dd   = 768;
static constexpr int HDm  = 96;
static constexpr int DFFc = 3072;
static constexpr int MROWS = Bb * Ss;  // 16384
static constexpr int NBK  = 64;
static constexpr int Hh   = 8;
static constexpr int QLD  = 2304;      // fused QKV row stride

typedef float f32x4_t __attribute__((ext_vector_type(4)));
typedef short s16x8_t __attribute__((ext_vector_type(8)));

__device__ __forceinline__ unsigned short f2bf(float f) {
  union { float f; unsigned int u; } c; c.f = f;
  unsigned int u = c.u;
  unsigned int r = (u + 0x7FFFu + ((u >> 16) & 1u)) >> 16;
  return (unsigned short)r;
}
__device__ __forceinline__ float bf2f(unsigned short u) {
  union { unsigned int u; float f; } c; c.u = ((unsigned int)u) << 16;
  return c.f;
}

// async global->LDS, 16B per lane; dst is wave-uniform base, lane i lands at
// dst + i*16 (guide §5; m97). src is per-lane.
__device__ __forceinline__ void gload16(const void* g, void* l) {
  __builtin_amdgcn_global_load_lds(
      (const __attribute__((address_space(1))) void*)g,
      (__attribute__((address_space(3))) void*)l, 16, 0, 0);
}

// ---------------------------------------------------------------------------
// Weight transpose+cast: src fp32 [K][N] -> dst bf16 [N][K]. 64x64 tiles.
// ---------------------------------------------------------------------------
__global__ __launch_bounds__(256)
void transpose_cast(const float* __restrict__ src, unsigned short* __restrict__ dst,
                    int K, int N) {
  __shared__ float t[64][65];
  const int n0 = blockIdx.x * 64, k0 = blockIdx.y * 64;
  const int tid = threadIdx.x;
  {
    const int r = tid >> 2, cs = (tid & 3) * 16;
    const float* sp = src + (size_t)(k0 + r) * N + n0 + cs;
#pragma unroll
    for (int u = 0; u < 4; u++) {
      float4 v = *(const float4*)(sp + u * 4);
      t[r][cs + u * 4 + 0] = v.x; t[r][cs + u * 4 + 1] = v.y;
      t[r][cs + u * 4 + 2] = v.z; t[r][cs + u * 4 + 3] = v.w;
    }
  }
  __syncthreads();
  {
    const int n = tid >> 2, ks = (tid & 3) * 16;
    unsigned short o[16];
#pragma unroll
    for (int j = 0; j < 16; j++) o[j] = f2bf(t[ks + j][n]);
    unsigned short* dp = dst + (size_t)(n0 + n) * K + k0 + ks;
    *(uint4*)(dp)     = *(uint4*)(o);
    *(uint4*)(dp + 8) = *(uint4*)(o + 8);
  }
}

// ---------------------------------------------------------------------------
// LayerNorm: fp32 in, bf16 out. 192 threads/row.
// ---------------------------------------------------------------------------
__global__ __launch_bounds__(192)
void ln_kernel(const float* __restrict__ x, const float* __restrict__ g,
               const float* __restrict__ beta, unsigned short* __restrict__ out) {
  const int row = blockIdx.x;
  const int t = threadIdx.x;
  const float* xr = x + (size_t)row * Dd;
  float4 v = *(const float4*)(xr + t * 4);
  float s  = v.x + v.y + v.z + v.w;
  float sq = v.x * v.x + v.y * v.y + v.z * v.z + v.w * v.w;
#pragma unroll
  for (int o = 32; o; o >>= 1) {
    s  += __shfl_xor(s, o);
    sq += __shfl_xor(sq, o);
  }
  __shared__ float rs[4], rq[4];
  const int w = t >> 6;
  if ((t & 63) == 0) { rs[w] = s; rq[w] = sq; }
  __syncthreads();
  s  = rs[0] + rs[1] + rs[2];
  sq = rq[0] + rq[1] + rq[2];
  const float mean = s * (1.0f / Dd);
  const float var  = sq * (1.0f / Dd) - mean * mean;
  const float rstd = rsqrtf(var + 1e-5f);
  float4 gv = *(const float4*)(g + t * 4);
  float4 bv = *(const float4*)(beta + t * 4);
  ushort4 o;
  o.x = f2bf((v.x - mean) * rstd * gv.x + bv.x);
  o.y = f2bf((v.y - mean) * rstd * gv.y + bv.y);
  o.z = f2bf((v.z - mean) * rstd * gv.z + bv.z);
  o.w = f2bf((v.w - mean) * rstd * gv.w + bv.w);
  *(ushort4*)(out + (size_t)row * Dd + t * 4) = o;
}

// ---------------------------------------------------------------------------
// BF16 MFMA GEMM, m97 structure: C[M,N] = act(A[M,K(lda)] @ Bt[N,K]^T + bias
// (+ fp32 resid)). Tile 128x128, BK=32, double-buffered LINEAR LDS staged via
// global_load_lds(16B), one barrier per K-step. 4 waves (2x2), 64x64/wave.
// Grid: 1D, XCD-bijective swizzle + within-XCD 2D chunking.
// Epilogue: per-wave LDS C-staging -> 16B stores.
// ---------------------------------------------------------------------------
template <int RELU, int OUTBF16, int RESID, int SEL3>
__global__ __launch_bounds__(256)
void bgemm(const unsigned short* __restrict__ A, const unsigned short* __restrict__ Bt,
           const float* __restrict__ b0, const float* __restrict__ b1,
           const float* __restrict__ b2, const float* __restrict__ resid,
           float* __restrict__ Cf, unsigned short* __restrict__ Cb,
           int N, int K, int lda, int GX) {
  __shared__ __align__(16) unsigned short lds[2][2][128][32];  // [buf][A/B][row][k]
  const int tid = threadIdx.x;

  // --- block swizzle: XCD-contiguous, 6-wide bx groups, by-mid ---
  const int nwg = gridDim.x;
  const int GYc = (nwg / GX) >> 3;           // per-XCD y-chunk
  const int xcd = blockIdx.x & 7;
  const int t0  = blockIdx.x >> 3;
  const int bxg = t0 / (6 * GYc);
  const int rr_ = t0 - bxg * 6 * GYc;
  const int by  = xcd * GYc + rr_ / 6;
  const int bx  = bxg * 6 + rr_ % 6;
  const int n0 = bx * 128, m0 = by * 128;

  const int lane = tid & 63, w = tid >> 6;
  const int wr = (w >> 1) * 64, wc = (w & 1) * 64;
  const int fr = lane & 15, fq = lane >> 4;
  const int l4 = lane >> 2, lc = (lane & 3) * 8;   // staging row / k-offset

  // staging bases: wave w covers rows [w*32, w*32+32) of the A and B tiles
  const unsigned short* Ab = A + (size_t)(m0 + w * 32 + l4) * lda + lc;
  const unsigned short* Bb2 = Bt + (size_t)(n0 + w * 32 + l4) * K + lc;
  const size_t a16 = (size_t)16 * lda, b16 = (size_t)16 * K;

  f32x4_t acc[4][4];
#pragma unroll
  for (int i = 0; i < 4; i++)
#pragma unroll
    for (int j = 0; j < 4; j++) acc[i][j] = (f32x4_t)0.0f;

  const int NT = K >> 5;
  int cur = 0;
  // prologue: stage tile 0
  gload16(Ab,        &lds[0][0][w * 32][0]);
  gload16(Ab + a16,  &lds[0][0][w * 32 + 16][0]);
  gload16(Bb2,       &lds[0][1][w * 32][0]);
  gload16(Bb2 + b16, &lds[0][1][w * 32 + 16][0]);
  __syncthreads();

  for (int t = 0; t < NT; t++) {
    if (t + 1 < NT) {  // stage next tile into other buffer (in flight over compute)
      const int ko = (t + 1) << 5;
      gload16(Ab + ko,        &lds[cur ^ 1][0][w * 32][0]);
      gload16(Ab + a16 + ko,  &lds[cur ^ 1][0][w * 32 + 16][0]);
      gload16(Bb2 + ko,       &lds[cur ^ 1][1][w * 32][0]);
      gload16(Bb2 + b16 + ko, &lds[cur ^ 1][1][w * 32 + 16][0]);
    }
    s16x8_t af[4], bf[4];
#pragma unroll
    for (int i = 0; i < 4; i++)
      af[i] = *(const s16x8_t*)&lds[cur][0][wr + i * 16 + fr][fq * 8];
#pragma unroll
    for (int j = 0; j < 4; j++)
      bf[j] = *(const s16x8_t*)&lds[cur][1][wc + j * 16 + fr][fq * 8];
#pragma unroll
    for (int i = 0; i < 4; i++)
#pragma unroll
      for (int j = 0; j < 4; j++)
        acc[i][j] = __builtin_amdgcn_mfma_f32_16x16x32_bf16(af[i], bf[j],
                                                            acc[i][j], 0, 0, 0);
    __syncthreads();  // drains stage (vmcnt) + compute reads (lgkm) before swap
    cur ^= 1;
  }

  // ---- Epilogue: stage C through per-wave LDS slab, vectorized stores ----
  constexpr int CLD = 76;
  float* cs = (float*)(&lds[0][0][0][0]) + w * (16 * CLD);

#pragma unroll
  for (int i = 0; i < 4; i++) {
#pragma unroll
    for (int j = 0; j < 4; j++) {
      const int col = n0 + wc + j * 16 + fr;
      float bc;
      if (SEL3)
        bc = col < 768 ? b0[col] : (col < 1536 ? b1[col - 768] : b2[col - 1536]);
      else
        bc = b0[col];
#pragma unroll
      for (int r4 = 0; r4 < 4; r4++) {
        float v = acc[i][j][r4] + bc;
        if (RELU) v = fmaxf(v, 0.0f);
        cs[(fq * 4 + r4) * CLD + j * 16 + fr] = v;
      }
    }
    if (OUTBF16) {
#pragma unroll
      for (int u = 0; u < 2; u++) {
        const int rr = (lane >> 3) + u * 8;
        const int c0 = (lane & 7) * 8;
        float4 x0 = *(float4*)&cs[rr * CLD + c0];
        float4 x1 = *(float4*)&cs[rr * CLD + c0 + 4];
        unsigned short o[8];
        o[0] = f2bf(x0.x); o[1] = f2bf(x0.y); o[2] = f2bf(x0.z); o[3] = f2bf(x0.w);
        o[4] = f2bf(x1.x); o[5] = f2bf(x1.y); o[6] = f2bf(x1.z); o[7] = f2bf(x1.w);
        *(uint4*)(Cb + (size_t)(m0 + wr + i * 16 + rr) * N + n0 + wc + c0) =
            *(uint4*)o;
      }
    } else {
#pragma unroll
      for (int u = 0; u < 4; u++) {
        const int rr = (lane >> 4) + u * 4;
        const int c0 = (lane & 15) * 4;
        const size_t off = (size_t)(m0 + wr + i * 16 + rr) * N + n0 + wc + c0;
        float4 x = *(float4*)&cs[rr * CLD + c0];
        if (RESID) {
          float4 r = *(const float4*)(resid + off);
          x.x += r.x; x.y += r.y; x.z += r.z; x.w += r.w;
        }
        *(float4*)(Cf + off) = x;
      }
    }
    __syncthreads();
  }
}

// ---------------------------------------------------------------------------
// BigBird block-sparse attention, MFMA version (unchanged from round 7).
// ---------------------------------------------------------------------------
__global__ __launch_bounds__(256)
void attn_mfma(const unsigned short* __restrict__ qkv,
               const int* __restrict__ kbidx,
               unsigned short* __restrict__ ctx) {
  const int bid = blockIdx.x;
  const int n = bid & 63;
  const int h = (bid >> 6) & 7;
  const int b = bid >> 9;
  const int tid = threadIdx.x;
  const int w = tid >> 6, lane = tid & 63;
  const int fr = lane & 15, fq = lane >> 4;

  __shared__ __align__(16) unsigned short Ks[64][104];  // keys x dims
  __shared__ __align__(16) unsigned short Vt[96][72];   // dims x keys
  __shared__ __align__(16) unsigned short Ps[64][72];   // qrows x keys

  s16x8_t qa[3];
  {
    const unsigned short* qrow =
        qkv + ((size_t)(b * Ss) + n * 64 + w * 16 + fr) * QLD + h * HDm;
#pragma unroll
    for (int kq = 0; kq < 3; kq++)
      qa[kq] = *(const s16x8_t*)(qrow + kq * 32 + fq * 8);
  }

  f32x4_t o_acc[6];
#pragma unroll
  for (int dt = 0; dt < 6; dt++) o_acc[dt] = (f32x4_t)0.0f;
  float m_run[4] = {-1e30f, -1e30f, -1e30f, -1e30f};
  float l_run[4] = {0.0f, 0.0f, 0.0f, 0.0f};
  const float scale = 0.1020620726f;  // 1/sqrt(96)

  for (int s = 0; s < 5; s++) {
    const int kb = kbidx[n * 5 + s];
    if (!(s == 0 || kb != 0)) continue;
    const bool diag = (kb == n);

    __syncthreads();
    {
      const unsigned short* kbase =
          qkv + 768 + ((size_t)(b * Ss) + kb * 64) * QLD + h * HDm;
#pragma unroll
      for (int u = 0; u < 3; u++) {
        const int c = tid + 256 * u;
        const int row = c / 12, d0 = (c % 12) * 8;
        *(uint4*)&Ks[row][d0] = *(const uint4*)(kbase + (size_t)row * QLD + d0);
      }
    }
    {
      const unsigned short* vbase =
          qkv + 1536 + ((size_t)(b * Ss) + kb * 64 + lane) * QLD + h * HDm + w * 24;
      unsigned short va[24];
      *(uint4*)&va[0]  = *(const uint4*)(vbase);
      *(uint4*)&va[8]  = *(const uint4*)(vbase + 8);
      *(uint4*)&va[16] = *(const uint4*)(vbase + 16);
#pragma unroll
      for (int j = 0; j < 24; j++) Vt[w * 24 + j][lane] = va[j];
    }
    __syncthreads();

    f32x4_t sf[4];
#pragma unroll
    for (int jt = 0; jt < 4; jt++) {
      sf[jt] = (f32x4_t)0.0f;
#pragma unroll
      for (int kq = 0; kq < 3; kq++) {
        s16x8_t kf = *(const s16x8_t*)&Ks[jt * 16 + fr][kq * 32 + fq * 8];
        sf[jt] = __builtin_amdgcn_mfma_f32_16x16x32_bf16(qa[kq], kf, sf[jt], 0, 0, 0);
      }
    }

    float p[4][4];
    float mt[4] = {-1e30f, -1e30f, -1e30f, -1e30f};
#pragma unroll
    for (int jt = 0; jt < 4; jt++)
#pragma unroll
      for (int r = 0; r < 4; r++) {
        float v = sf[jt][r] * scale;
        if (diag && (jt * 16 + fr) > (w * 16 + fq * 4 + r)) v = -1e9f;
        p[jt][r] = v;
        mt[r] = fmaxf(mt[r], v);
      }
#pragma unroll
    for (int off = 1; off < 16; off <<= 1)
#pragma unroll
      for (int r = 0; r < 4; r++) mt[r] = fmaxf(mt[r], __shfl_xor(mt[r], off));
    float fsc[4], rs[4];
#pragma unroll
    for (int r = 0; r < 4; r++) {
      const float mnew = fmaxf(m_run[r], mt[r]);
      fsc[r] = __expf(m_run[r] - mnew);
      m_run[r] = mnew;
      float s0 = 0.0f;
#pragma unroll
      for (int jt = 0; jt < 4; jt++) {
        p[jt][r] = __expf(p[jt][r] - mnew);
        s0 += p[jt][r];
      }
      rs[r] = s0;
    }
#pragma unroll
    for (int off = 1; off < 16; off <<= 1)
#pragma unroll
      for (int r = 0; r < 4; r++) rs[r] += __shfl_xor(rs[r], off);
#pragma unroll
    for (int r = 0; r < 4; r++) l_run[r] = l_run[r] * fsc[r] + rs[r];
#pragma unroll
    for (int dt = 0; dt < 6; dt++)
#pragma unroll
      for (int r = 0; r < 4; r++) o_acc[dt][r] *= fsc[r];

#pragma unroll
    for (int jt = 0; jt < 4; jt++)
#pragma unroll
      for (int r = 0; r < 4; r++)
        Ps[w * 16 + fq * 4 + r][jt * 16 + fr] = f2bf(p[jt][r]);

    s16x8_t pf[2];
#pragma unroll
    for (int k2 = 0; k2 < 2; k2++)
      pf[k2] = *(const s16x8_t*)&Ps[w * 16 + fr][k2 * 32 + fq * 8];
#pragma unroll
    for (int dt = 0; dt < 6; dt++)
#pragma unroll
      for (int k2 = 0; k2 < 2; k2++) {
        s16x8_t vf = *(const s16x8_t*)&Vt[dt * 16 + fr][k2 * 32 + fq * 8];
        o_acc[dt] = __builtin_amdgcn_mfma_f32_16x16x32_bf16(pf[k2], vf, o_acc[dt], 0, 0, 0);
      }
  }

#pragma unroll
  for (int r = 0; r < 4; r++) {
    const float inv = 1.0f / l_run[r];
    unsigned short* dst =
        ctx + ((size_t)(b * Ss) + n * 64 + w * 16 + fq * 4 + r) * QLD + h * HDm;
#pragma unroll
    for (int dt = 0; dt < 6; dt++)
      dst[dt * 16 + fr] = f2bf(o_acc[dt][r] * inv);
  }
}

// ---------------------------------------------------------------------------
// Host launcher. ws layout (ushorts), total 69,992,448 (133.5 MiB):
//   WqkvT [2304][768] | Wot [768][768] | W1t [3072][768] | W2t [768][3072]
//   h [16384][768] | pool: fused QKV [16384][2304] -> later fbuf [16384][3072]
// x1 lives in d_out fp32.
// ---------------------------------------------------------------------------
extern "C" void kernel_launch(void* const* d_in, const int* in_sizes, int n_in,
                              void* d_out, int out_size, void* d_ws, size_t ws_size,
                              hipStream_t stream) {
  const float* x    = (const float*)d_in[0];
  const float* Wq   = (const float*)d_in[1];
  const float* bq   = (const float*)d_in[2];
  const float* Wk   = (const float*)d_in[3];
  const float* bk   = (const float*)d_in[4];
  const float* Wv   = (const float*)d_in[5];
  const float* bv   = (const float*)d_in[6];
  const float* Wo   = (const float*)d_in[7];
  const float* bo   = (const float*)d_in[8];
  const float* ln_g = (const float*)d_in[9];
  const float* ln_b = (const float*)d_in[10];
  const float* W1   = (const float*)d_in[11];
  const float* b1   = (const float*)d_in[12];
  const float* W2   = (const float*)d_in[13];
  const float* b2   = (const float*)d_in[14];
  const int*   kb   = (const int*)d_in[15];

  float* out = (float*)d_out;
  unsigned short* ws = (unsigned short*)d_ws;

  constexpr size_t WSQ = (size_t)Dd * Dd;
  unsigned short* WqkvT = ws;
  unsigned short* Wot   = WqkvT + 3 * WSQ;
  unsigned short* W1t   = Wot + WSQ;
  unsigned short* W2t   = W1t + (size_t)Dd * DFFc;
  unsigned short* h     = W2t + (size_t)Dd * DFFc;
  unsigned short* pool  = h + (size_t)MROWS * Dd;
  unsigned short* fused = pool;                     // [MROWS][2304]
  unsigned short* fbuf  = pool;                     // [MROWS][3072] (after attn)

  // 0. Weight transpose+cast (bf16 [N][K]); QKV concatenated row-wise.
  transpose_cast<<<dim3(12, 12), 256, 0, stream>>>(Wq, WqkvT,           Dd, Dd);
  transpose_cast<<<dim3(12, 12), 256, 0, stream>>>(Wk, WqkvT + WSQ,     Dd, Dd);
  transpose_cast<<<dim3(12, 12), 256, 0, stream>>>(Wv, WqkvT + 2 * WSQ, Dd, Dd);
  transpose_cast<<<dim3(12, 12), 256, 0, stream>>>(Wo, Wot,             Dd, Dd);
  transpose_cast<<<dim3(48, 12), 256, 0, stream>>>(W1, W1t, Dd, DFFc);
  transpose_cast<<<dim3(12, 48), 256, 0, stream>>>(W2, W2t, DFFc, Dd);

  // 1. h = LN(x) -> bf16
  ln_kernel<<<MROWS, 192, 0, stream>>>(x, ln_g, ln_b, h);

  // 2. fused QKV: [M,2304] = h @ WqkvT^T  (bias 3-way select)
  bgemm<0, 1, 0, 1><<<2304, 256, 0, stream>>>(
      h, WqkvT, bq, bk, bv, nullptr, nullptr, fused, QLD, Dd, Dd, 18);

  // 3. attention (MFMA; ctx in place over q-section of fused)
  attn_mfma<<<Bb * Hh * NBK, 256, 0, stream>>>(fused, kb, fused);

  // 4. out = x + ctx @ Wo + bo   (fp32; A = fused q-section, lda=2304)
  bgemm<0, 0, 1, 0><<<768, 256, 0, stream>>>(
      fused, Wot, bo, nullptr, nullptr, x, out, nullptr, Dd, Dd, QLD, 6);

  // 5. h = LN(out) -> bf16
  ln_kernel<<<MROWS, 192, 0, stream>>>(out, ln_g, ln_b, h);

  // 6. fbuf = relu(h @ W1 + b1) -> bf16   [16384][3072]
  bgemm<1, 1, 0, 0><<<3072, 256, 0, stream>>>(
      h, W1t, b1, nullptr, nullptr, nullptr, nullptr, fbuf, DFFc, Dd, Dd, 24);

  // 7. out += fbuf @ W2 + b2   (fp32, in-place resid)
  bgemm<0, 0, 1, 0><<<768, 256, 0, stream>>>(
      fbuf, W2t, b2, nullptr, nullptr, out, out, nullptr, Dd, DFFc, DFFc, 6);
}

// Round 9
// 533.106 us; speedup vs baseline: 6.4841x; 1.0637x over previous
//
#include <hip/hip_runtime.h>
#include <math.h>

// B=4 S=4096 D=768 H=8 BS=64 NB=64 NKB=5 HD=96 DFF=3072
static constexpr int Bb   = 4;
static constexpr int Ss   = 4096;
static constexpr int Dd   = 768;
static constexpr int HDm  = 96;
static constexpr int DFFc = 3072;
static constexpr int MROWS = Bb * Ss;  // 16384
static constexpr int NBK  = 64;
static constexpr int Hh   = 8;
static constexpr int QLD  = 2304;      // fused QKV row stride

typedef float f32x4_t __attribute__((ext_vector_type(4)));
typedef short s16x8_t __attribute__((ext_vector_type(8)));

__device__ __forceinline__ unsigned short f2bf(float f) {
  union { float f; unsigned int u; } c; c.f = f;
  unsigned int u = c.u;
  unsigned int r = (u + 0x7FFFu + ((u >> 16) & 1u)) >> 16;
  return (unsigned short)r;
}
__device__ __forceinline__ float bf2f(unsigned short u) {
  union { unsigned int u; float f; } c; c.u = ((unsigned int)u) << 16;
  return c.f;
}

// async global->LDS, 16B per lane; dst is wave-uniform base, lane i lands at
// dst + i*16 (guide §5; m97). src is per-lane.
__device__ __forceinline__ void gload16(const void* g, void* l) {
  __builtin_amdgcn_global_load_lds(
      (const __attribute__((address_space(1))) void*)g,
      (__attribute__((address_space(3))) void*)l, 16, 0, 0);
}

// ---------------------------------------------------------------------------
// Weight transpose+cast: src fp32 [K][N] -> dst bf16 [N][K]. 64x64 tiles.
// ---------------------------------------------------------------------------
__global__ __launch_bounds__(256)
void transpose_cast(const float* __restrict__ src, unsigned short* __restrict__ dst,
                    int K, int N) {
  __shared__ float t[64][65];
  const int n0 = blockIdx.x * 64, k0 = blockIdx.y * 64;
  const int tid = threadIdx.x;
  {
    const int r = tid >> 2, cs = (tid & 3) * 16;
    const float* sp = src + (size_t)(k0 + r) * N + n0 + cs;
#pragma unroll
    for (int u = 0; u < 4; u++) {
      float4 v = *(const float4*)(sp + u * 4);
      t[r][cs + u * 4 + 0] = v.x; t[r][cs + u * 4 + 1] = v.y;
      t[r][cs + u * 4 + 2] = v.z; t[r][cs + u * 4 + 3] = v.w;
    }
  }
  __syncthreads();
  {
    const int n = tid >> 2, ks = (tid & 3) * 16;
    unsigned short o[16];
#pragma unroll
    for (int j = 0; j < 16; j++) o[j] = f2bf(t[ks + j][n]);
    unsigned short* dp = dst + (size_t)(n0 + n) * K + k0 + ks;
    *(uint4*)(dp)     = *(uint4*)(o);
    *(uint4*)(dp + 8) = *(uint4*)(o + 8);
  }
}

// ---------------------------------------------------------------------------
// LayerNorm: fp32 in, bf16 out. 192 threads/row.
// ---------------------------------------------------------------------------
__global__ __launch_bounds__(192)
void ln_kernel(const float* __restrict__ x, const float* __restrict__ g,
               const float* __restrict__ beta, unsigned short* __restrict__ out) {
  const int row = blockIdx.x;
  const int t = threadIdx.x;
  const float* xr = x + (size_t)row * Dd;
  float4 v = *(const float4*)(xr + t * 4);
  float s  = v.x + v.y + v.z + v.w;
  float sq = v.x * v.x + v.y * v.y + v.z * v.z + v.w * v.w;
#pragma unroll
  for (int o = 32; o; o >>= 1) {
    s  += __shfl_xor(s, o);
    sq += __shfl_xor(sq, o);
  }
  __shared__ float rs[4], rq[4];
  const int w = t >> 6;
  if ((t & 63) == 0) { rs[w] = s; rq[w] = sq; }
  __syncthreads();
  s  = rs[0] + rs[1] + rs[2];
  sq = rq[0] + rq[1] + rq[2];
  const float mean = s * (1.0f / Dd);
  const float var  = sq * (1.0f / Dd) - mean * mean;
  const float rstd = rsqrtf(var + 1e-5f);
  float4 gv = *(const float4*)(g + t * 4);
  float4 bv = *(const float4*)(beta + t * 4);
  ushort4 o;
  o.x = f2bf((v.x - mean) * rstd * gv.x + bv.x);
  o.y = f2bf((v.y - mean) * rstd * gv.y + bv.y);
  o.z = f2bf((v.z - mean) * rstd * gv.z + bv.z);
  o.w = f2bf((v.w - mean) * rstd * gv.w + bv.w);
  *(ushort4*)(out + (size_t)row * Dd + t * 4) = o;
}

// ---------------------------------------------------------------------------
// BF16 MFMA GEMM, counted-vmcnt ring pipeline:
// C[M,N] = act(A[M,K(lda)] @ Bt[N,K]^T + bias (+ fp32 resid)).
// Tile 128x128, BK=32, 3-slot LDS ring staged via global_load_lds(16B).
// Per iter: vmcnt(4) [tile t landed, t+1 stays IN FLIGHT across barrier] ->
// s_barrier -> stage(t+2) into slot (t+2)%3 [safe: last read iter t-1, all
// waves' reads consumed before they entered this barrier] -> ds_read -> MFMA.
// Never vmcnt(0) in the main loop (T4); last iteration peeled with vmcnt(0).
// 4 waves (2x2), 64x64/wave. Grid: 1D, XCD-bijective swizzle + 2D chunking.
// Epilogue: per-wave LDS C-staging -> 16B stores.
// ---------------------------------------------------------------------------
template <int RELU, int OUTBF16, int RESID, int SEL3>
__global__ __launch_bounds__(256)
void bgemm(const unsigned short* __restrict__ A, const unsigned short* __restrict__ Bt,
           const float* __restrict__ b0, const float* __restrict__ b1,
           const float* __restrict__ b2, const float* __restrict__ resid,
           float* __restrict__ Cf, unsigned short* __restrict__ Cb,
           int N, int K, int lda, int GX) {
  __shared__ __align__(16) unsigned short ring[3][2][128][32];  // [slot][A/B][row][k]
  const int tid = threadIdx.x;

  // --- block swizzle: XCD-contiguous, 6-wide bx groups, by-mid ---
  const int nwg = gridDim.x;
  const int GYc = (nwg / GX) >> 3;           // per-XCD y-chunk
  const int xcd = blockIdx.x & 7;
  const int t0  = blockIdx.x >> 3;
  const int bxg = t0 / (6 * GYc);
  const int rr_ = t0 - bxg * 6 * GYc;
  const int by  = xcd * GYc + rr_ / 6;
  const int bx  = bxg * 6 + rr_ % 6;
  const int n0 = bx * 128, m0 = by * 128;

  const int lane = tid & 63, w = tid >> 6;
  const int wr = (w >> 1) * 64, wc = (w & 1) * 64;
  const int fr = lane & 15, fq = lane >> 4;
  const int l4 = lane >> 2, lc = (lane & 3) * 8;   // staging row / k-offset

  // staging bases: wave w covers rows [w*32, w*32+32) of the A and B tiles
  const unsigned short* Ab = A + (size_t)(m0 + w * 32 + l4) * lda + lc;
  const unsigned short* Bb2 = Bt + (size_t)(n0 + w * 32 + l4) * K + lc;
  const size_t a16 = (size_t)16 * lda, b16 = (size_t)16 * K;

  f32x4_t acc[4][4];
#pragma unroll
  for (int i = 0; i < 4; i++)
#pragma unroll
    for (int j = 0; j < 4; j++) acc[i][j] = (f32x4_t)0.0f;

  const int NT = K >> 5;

  // 4 load-instructions per tile per wave (vmcnt counts per-wave VMEM ops)
#define STAGE(kt, slot)                                         \
  {                                                             \
    const int ko_ = (kt) << 5;                                  \
    gload16(Ab + ko_,        &ring[slot][0][w * 32][0]);        \
    gload16(Ab + a16 + ko_,  &ring[slot][0][w * 32 + 16][0]);   \
    gload16(Bb2 + ko_,       &ring[slot][1][w * 32][0]);        \
    gload16(Bb2 + b16 + ko_, &ring[slot][1][w * 32 + 16][0]);   \
  }

#define COMPUTE(slot)                                                          \
  {                                                                            \
    s16x8_t af[4], bf[4];                                                      \
    _Pragma("unroll") for (int i = 0; i < 4; i++)                              \
        af[i] = *(const s16x8_t*)&ring[slot][0][wr + i * 16 + fr][fq * 8];     \
    _Pragma("unroll") for (int j = 0; j < 4; j++)                              \
        bf[j] = *(const s16x8_t*)&ring[slot][1][wc + j * 16 + fr][fq * 8];     \
    _Pragma("unroll") for (int i = 0; i < 4; i++)                              \
        _Pragma("unroll") for (int j = 0; j < 4; j++)                          \
            acc[i][j] = __builtin_amdgcn_mfma_f32_16x16x32_bf16(af[i], bf[j],  \
                                                                acc[i][j], 0, 0, 0); \
  }

  // prologue: stage tiles 0 and 1
  STAGE(0, 0);
  STAGE(1, 1);

  int rb = 0;
  for (int t = 0; t < NT - 1; t++) {
    // own tile-t loads landed; tile t+1's 4 loads stay in flight across barrier
    asm volatile("s_waitcnt vmcnt(4)" ::: "memory");
    __builtin_amdgcn_s_barrier();
    asm volatile("" ::: "memory");
    if (t + 2 < NT) {
      int nb = rb + 2; if (nb >= 3) nb -= 3;
      STAGE(t + 2, nb);
    }
    COMPUTE(rb);
    rb = (rb + 1 == 3) ? 0 : rb + 1;
  }
  // peeled last iteration: drain everything
  asm volatile("s_waitcnt vmcnt(0)" ::: "memory");
  __builtin_amdgcn_s_barrier();
  asm volatile("" ::: "memory");
  COMPUTE(rb);
  __syncthreads();  // all reads done before epilogue reuses LDS

#undef STAGE
#undef COMPUTE

  // ---- Epilogue: stage C through per-wave LDS slab, vectorized stores ----
  constexpr int CLD = 76;
  float* cs = (float*)(&ring[0][0][0][0]) + w * (16 * CLD);

#pragma unroll
  for (int i = 0; i < 4; i++) {
#pragma unroll
    for (int j = 0; j < 4; j++) {
      const int col = n0 + wc + j * 16 + fr;
      float bc;
      if (SEL3)
        bc = col < 768 ? b0[col] : (col < 1536 ? b1[col - 768] : b2[col - 1536]);
      else
        bc = b0[col];
#pragma unroll
      for (int r4 = 0; r4 < 4; r4++) {
        float v = acc[i][j][r4] + bc;
        if (RELU) v = fmaxf(v, 0.0f);
        cs[(fq * 4 + r4) * CLD + j * 16 + fr] = v;
      }
    }
    if (OUTBF16) {
#pragma unroll
      for (int u = 0; u < 2; u++) {
        const int rr = (lane >> 3) + u * 8;
        const int c0 = (lane & 7) * 8;
        float4 x0 = *(float4*)&cs[rr * CLD + c0];
        float4 x1 = *(float4*)&cs[rr * CLD + c0 + 4];
        unsigned short o[8];
        o[0] = f2bf(x0.x); o[1] = f2bf(x0.y); o[2] = f2bf(x0.z); o[3] = f2bf(x0.w);
        o[4] = f2bf(x1.x); o[5] = f2bf(x1.y); o[6] = f2bf(x1.z); o[7] = f2bf(x1.w);
        *(uint4*)(Cb + (size_t)(m0 + wr + i * 16 + rr) * N + n0 + wc + c0) =
            *(uint4*)o;
      }
    } else {
#pragma unroll
      for (int u = 0; u < 4; u++) {
        const int rr = (lane >> 4) + u * 4;
        const int c0 = (lane & 15) * 4;
        const size_t off = (size_t)(m0 + wr + i * 16 + rr) * N + n0 + wc + c0;
        float4 x = *(float4*)&cs[rr * CLD + c0];
        if (RESID) {
          float4 r = *(const float4*)(resid + off);
          x.x += r.x; x.y += r.y; x.z += r.z; x.w += r.w;
        }
        *(float4*)(Cf + off) = x;
      }
    }
    __syncthreads();
  }
}

// ---------------------------------------------------------------------------
// BigBird block-sparse attention, MFMA version (unchanged from round 7).
// ---------------------------------------------------------------------------
__global__ __launch_bounds__(256)
void attn_mfma(const unsigned short* __restrict__ qkv,
               const int* __restrict__ kbidx,
               unsigned short* __restrict__ ctx) {
  const int bid = blockIdx.x;
  const int n = bid & 63;
  const int h = (bid >> 6) & 7;
  const int b = bid >> 9;
  const int tid = threadIdx.x;
  const int w = tid >> 6, lane = tid & 63;
  const int fr = lane & 15, fq = lane >> 4;

  __shared__ __align__(16) unsigned short Ks[64][104];  // keys x dims
  __shared__ __align__(16) unsigned short Vt[96][72];   // dims x keys
  __shared__ __align__(16) unsigned short Ps[64][72];   // qrows x keys

  s16x8_t qa[3];
  {
    const unsigned short* qrow =
        qkv + ((size_t)(b * Ss) + n * 64 + w * 16 + fr) * QLD + h * HDm;
#pragma unroll
    for (int kq = 0; kq < 3; kq++)
      qa[kq] = *(const s16x8_t*)(qrow + kq * 32 + fq * 8);
  }

  f32x4_t o_acc[6];
#pragma unroll
  for (int dt = 0; dt < 6; dt++) o_acc[dt] = (f32x4_t)0.0f;
  float m_run[4] = {-1e30f, -1e30f, -1e30f, -1e30f};
  float l_run[4] = {0.0f, 0.0f, 0.0f, 0.0f};
  const float scale = 0.1020620726f;  // 1/sqrt(96)

  for (int s = 0; s < 5; s++) {
    const int kb = kbidx[n * 5 + s];
    if (!(s == 0 || kb != 0)) continue;
    const bool diag = (kb == n);

    __syncthreads();
    {
      const unsigned short* kbase =
          qkv + 768 + ((size_t)(b * Ss) + kb * 64) * QLD + h * HDm;
#pragma unroll
      for (int u = 0; u < 3; u++) {
        const int c = tid + 256 * u;
        const int row = c / 12, d0 = (c % 12) * 8;
        *(uint4*)&Ks[row][d0] = *(const uint4*)(kbase + (size_t)row * QLD + d0);
      }
    }
    {
      const unsigned short* vbase =
          qkv + 1536 + ((size_t)(b * Ss) + kb * 64 + lane) * QLD + h * HDm + w * 24;
      unsigned short va[24];
      *(uint4*)&va[0]  = *(const uint4*)(vbase);
      *(uint4*)&va[8]  = *(const uint4*)(vbase + 8);
      *(uint4*)&va[16] = *(const uint4*)(vbase + 16);
#pragma unroll
      for (int j = 0; j < 24; j++) Vt[w * 24 + j][lane] = va[j];
    }
    __syncthreads();

    f32x4_t sf[4];
#pragma unroll
    for (int jt = 0; jt < 4; jt++) {
      sf[jt] = (f32x4_t)0.0f;
#pragma unroll
      for (int kq = 0; kq < 3; kq++) {
        s16x8_t kf = *(const s16x8_t*)&Ks[jt * 16 + fr][kq * 32 + fq * 8];
        sf[jt] = __builtin_amdgcn_mfma_f32_16x16x32_bf16(qa[kq], kf, sf[jt], 0, 0, 0);
      }
    }

    float p[4][4];
    float mt[4] = {-1e30f, -1e30f, -1e30f, -1e30f};
#pragma unroll
    for (int jt = 0; jt < 4; jt++)
#pragma unroll
      for (int r = 0; r < 4; r++) {
        float v = sf[jt][r] * scale;
        if (diag && (jt * 16 + fr) > (w * 16 + fq * 4 + r)) v = -1e9f;
        p[jt][r] = v;
        mt[r] = fmaxf(mt[r], v);
      }
#pragma unroll
    for (int off = 1; off < 16; off <<= 1)
#pragma unroll
      for (int r = 0; r < 4; r++) mt[r] = fmaxf(mt[r], __shfl_xor(mt[r], off));
    float fsc[4], rs[4];
#pragma unroll
    for (int r = 0; r < 4; r++) {
      const float mnew = fmaxf(m_run[r], mt[r]);
      fsc[r] = __expf(m_run[r] - mnew);
      m_run[r] = mnew;
      float s0 = 0.0f;
#pragma unroll
      for (int jt = 0; jt < 4; jt++) {
        p[jt][r] = __expf(p[jt][r] - mnew);
        s0 += p[jt][r];
      }
      rs[r] = s0;
    }
#pragma unroll
    for (int off = 1; off < 16; off <<= 1)
#pragma unroll
      for (int r = 0; r < 4; r++) rs[r] += __shfl_xor(rs[r], off);
#pragma unroll
    for (int r = 0; r < 4; r++) l_run[r] = l_run[r] * fsc[r] + rs[r];
#pragma unroll
    for (int dt = 0; dt < 6; dt++)
#pragma unroll
      for (int r = 0; r < 4; r++) o_acc[dt][r] *= fsc[r];

#pragma unroll
    for (int jt = 0; jt < 4; jt++)
#pragma unroll
      for (int r = 0; r < 4; r++)
        Ps[w * 16 + fq * 4 + r][jt * 16 + fr] = f2bf(p[jt][r]);

    s16x8_t pf[2];
#pragma unroll
    for (int k2 = 0; k2 < 2; k2++)
      pf[k2] = *(const s16x8_t*)&Ps[w * 16 + fr][k2 * 32 + fq * 8];
#pragma unroll
    for (int dt = 0; dt < 6; dt++)
#pragma unroll
      for (int k2 = 0; k2 < 2; k2++) {
        s16x8_t vf = *(const s16x8_t*)&Vt[dt * 16 + fr][k2 * 32 + fq * 8];
        o_acc[dt] = __builtin_amdgcn_mfma_f32_16x16x32_bf16(pf[k2], vf, o_acc[dt], 0, 0, 0);
      }
  }

#pragma unroll
  for (int r = 0; r < 4; r++) {
    const float inv = 1.0f / l_run[r];
    unsigned short* dst =
        ctx + ((size_t)(b * Ss) + n * 64 + w * 16 + fq * 4 + r) * QLD + h * HDm;
#pragma unroll
    for (int dt = 0; dt < 6; dt++)
      dst[dt * 16 + fr] = f2bf(o_acc[dt][r] * inv);
  }
}

// ---------------------------------------------------------------------------
// Host launcher. ws layout (ushorts), total 69,992,448 (133.5 MiB):
//   WqkvT [2304][768] | Wot [768][768] | W1t [3072][768] | W2t [768][3072]
//   h [16384][768] | pool: fused QKV [16384][2304] -> later fbuf [16384][3072]
// x1 lives in d_out fp32.
// ---------------------------------------------------------------------------
extern "C" void kernel_launch(void* const* d_in, const int* in_sizes, int n_in,
                              void* d_out, int out_size, void* d_ws, size_t ws_size,
                              hipStream_t stream) {
  const float* x    = (const float*)d_in[0];
  const float* Wq   = (const float*)d_in[1];
  const float* bq   = (const float*)d_in[2];
  const float* Wk   = (const float*)d_in[3];
  const float* bk   = (const float*)d_in[4];
  const float* Wv   = (const float*)d_in[5];
  const float* bv   = (const float*)d_in[6];
  const float* Wo   = (const float*)d_in[7];
  const float* bo   = (const float*)d_in[8];
  const float* ln_g = (const float*)d_in[9];
  const float* ln_b = (const float*)d_in[10];
  const float* W1   = (const float*)d_in[11];
  const float* b1   = (const float*)d_in[12];
  const float* W2   = (const float*)d_in[13];
  const float* b2   = (const float*)d_in[14];
  const int*   kb   = (const int*)d_in[15];

  float* out = (float*)d_out;
  unsigned short* ws = (unsigned short*)d_ws;

  constexpr size_t WSQ = (size_t)Dd * Dd;
  unsigned short* WqkvT = ws;
  unsigned short* Wot   = WqkvT + 3 * WSQ;
  unsigned short* W1t   = Wot + WSQ;
  unsigned short* W2t   = W1t + (size_t)Dd * DFFc;
  unsigned short* h     = W2t + (size_t)Dd * DFFc;
  unsigned short* pool  = h + (size_t)MROWS * Dd;
  unsigned short* fused = pool;                     // [MROWS][2304]
  unsigned short* fbuf  = pool;                     // [MROWS][3072] (after attn)

  // 0. Weight transpose+cast (bf16 [N][K]); QKV concatenated row-wise.
  transpose_cast<<<dim3(12, 12), 256, 0, stream>>>(Wq, WqkvT,           Dd, Dd);
  transpose_cast<<<dim3(12, 12), 256, 0, stream>>>(Wk, WqkvT + WSQ,     Dd, Dd);
  transpose_cast<<<dim3(12, 12), 256, 0, stream>>>(Wv, WqkvT + 2 * WSQ, Dd, Dd);
  transpose_cast<<<dim3(12, 12), 256, 0, stream>>>(Wo, Wot,             Dd, Dd);
  transpose_cast<<<dim3(48, 12), 256, 0, stream>>>(W1, W1t, Dd, DFFc);
  transpose_cast<<<dim3(12, 48), 256, 0, stream>>>(W2, W2t, DFFc, Dd);

  // 1. h = LN(x) -> bf16
  ln_kernel<<<MROWS, 192, 0, stream>>>(x, ln_g, ln_b, h);

  // 2. fused QKV: [M,2304] = h @ WqkvT^T  (bias 3-way select)
  bgemm<0, 1, 0, 1><<<2304, 256, 0, stream>>>(
      h, WqkvT, bq, bk, bv, nullptr, nullptr, fused, QLD, Dd, Dd, 18);

  // 3. attention (MFMA; ctx in place over q-section of fused)
  attn_mfma<<<Bb * Hh * NBK, 256, 0, stream>>>(fused, kb, fused);

  // 4. out = x + ctx @ Wo + bo   (fp32; A = fused q-section, lda=2304)
  bgemm<0, 0, 1, 0><<<768, 256, 0, stream>>>(
      fused, Wot, bo, nullptr, nullptr, x, out, nullptr, Dd, Dd, QLD, 6);

  // 5. h = LN(out) -> bf16
  ln_kernel<<<MROWS, 192, 0, stream>>>(out, ln_g, ln_b, h);

  // 6. fbuf = relu(h @ W1 + b1) -> bf16   [16384][3072]
  bgemm<1, 1, 0, 0><<<3072, 256, 0, stream>>>(
      h, W1t, b1, nullptr, nullptr, nullptr, nullptr, fbuf, DFFc, Dd, Dd, 24);

  // 7. out += fbuf @ W2 + b2   (fp32, in-place resid)
  bgemm<0, 0, 1, 0><<<768, 256, 0, stream>>>(
      fbuf, W2t, b2, nullptr, nullptr, out, out, nullptr, Dd, DFFc, DFFc, 6);
}